// Round 5
// baseline (638.688 us; speedup 1.0000x reference)
//
#include <hip/hip_runtime.h>
#include <hip/hip_bf16.h>
#include <math.h>

#define B_ 2
#define A_ 9
#define N_ 1024
#define P_ 4
#define D_ 256
#define H_ 8
#define DH_ 32
#define ROWS_ (B_*N_)   // 2048
#define KS_ 8           // K-split factor for chain
#define KSL_ (N_/KS_)   // 128 contraction elems per block
#define MH_ 1100        // ushort stride per head plane in LDS (550 dwords, 550%32=6 stagger)
#define MR_ 136         // ushort stride per row within a head plane
#define ADJ_ELEMS_ ((size_t)B_*A_*N_*N_)

__device__ __forceinline__ uint pack2_bf(float x, float y) {
    uint ux = __float_as_uint(x); ux += 0x7fffu + ((ux >> 16) & 1u);
    uint uy = __float_as_uint(y); uy += 0x7fffu + ((uy >> 16) & 1u);
    return (ux >> 16) | (uy & 0xffff0000u);
}

// ---------------- prep: softmax(relu(kernels)) over A axis + 1/diag(degree) ----------------
__global__ void prep_kernel(const float* __restrict__ kernels, const float* __restrict__ degree,
                            float* __restrict__ soft, float* __restrict__ invd)
{
    int t = threadIdx.x;
    if (blockIdx.x == 0) {
        if (t < H_*P_) {
            int h = t >> 2, p = t & 3;
            float vals[A_];
            float m = 0.0f;
            #pragma unroll
            for (int a = 0; a < A_; a++) {
                float v = kernels[h*A_*P_ + a*P_ + p];
                v = v > 0.0f ? v : 0.0f;
                vals[a] = v;
                m = fmaxf(m, v);
            }
            float s = 0.0f;
            #pragma unroll
            for (int a = 0; a < A_; a++) { vals[a] = expf(vals[a] - m); s += vals[a]; }
            float inv = 1.0f / s;
            #pragma unroll
            for (int a = 0; a < A_; a++) soft[h*A_*P_ + a*P_ + p] = vals[a] * inv;
        }
    } else {
        int idx = (blockIdx.x - 1) * 256 + t;
        if (idx < ROWS_) {
            int b = idx >> 10, n = idx & (N_-1);
            invd[idx] = 1.0f / degree[(size_t)b*N_*N_ + (size_t)n*N_ + n];
        }
    }
}

// ---------------- pack adjacency fp32 -> bf16 in block-consumption order ----------------
// dst layout: [b][rowblk(128)][ks(8)][a(9)][r(8)][kk(128)] bf16; one uint4 (8 bf16) per thread.
__global__ void adj_pack_kernel(const float* __restrict__ in, ushort* __restrict__ out)
{
    int j = blockIdx.x * 256 + threadIdx.x;   // uint4 index; grid covers ADJ_ELEMS_/8 exactly
    int kk8 = j & 15;
    int r   = (j >> 4) & 7;
    int t   = j >> 7;
    int a   = t % 9;
    int q   = t / 9;           // b*1024 + rowblk*8 + ks
    int ks  = q & 7;
    int rowblk = (q >> 3) & 127;
    int b   = q >> 10;
    int n = rowblk*8 + r;
    int m = ks*128 + kk8*8;
    const float* src = &in[(((size_t)b*A_ + a)*N_ + n)*N_ + m];
    float4 v0 = *(const float4*)src;
    float4 v1 = *(const float4*)(src + 4);
    uint4 o;
    o.x = pack2_bf(v0.x, v0.y);
    o.y = pack2_bf(v0.z, v0.w);
    o.z = pack2_bf(v1.x, v1.y);
    o.w = pack2_bf(v1.z, v1.w);
    ((uint4*)out)[j] = o;
}

// ---------------- chain (K-split, packed adjacency): Pp[ks] = M_step[:,slice] @ Tin[slice,:] ----
// grid = B*128*KS_ = 2048 blocks; 256 threads; block = 8 rows x 256 cols, k-depth 128.
// Compute mapping: head(2/wave) x e(8) x rsub(4); rsub = intra-block k-split (each (k,col) of the
// Tin slice loaded exactly ONCE -> 4x less L2 traffic than row-split). Cross-rsub partials reduced
// with a 2-stage shfl_xor butterfly (lanes differ in bits 3-4); each lane stores its 2-row share.
__global__ __launch_bounds__(256, 6)
void chain_kernel(const ushort* __restrict__ adjp, const float* __restrict__ soft,
                  const float* __restrict__ Tin, float* __restrict__ Pp, int step)
{
    __shared__ ushort Msb[8*MH_];     // 8 head planes of mixed M, bf16, bank-staggered
    __shared__ float soft_s[8][9];

    int bid    = blockIdx.x;
    int ks     = bid & (KS_-1);
    int rowblk = (bid >> 3) & 127;
    int b      = bid >> 10;
    int n0     = rowblk * 8;
    int tid    = threadIdx.x;

    if (tid < 72) {
        int h = tid / 9, a = tid % 9;
        soft_s[h][a] = soft[h*A_*P_ + a*P_ + step];
    }
    __syncthreads();

    // ---- mixing phase: thread owns (r = tid>>5, 4 consecutive kk); reads 9 relations ----
    {
        int r   = tid >> 5;
        int kkg = (tid & 31) * 4;
        const ushort* sl = adjp + (size_t)(((b*128 + rowblk)*8 + ks)*9) * (8*128);
        float va[9][4];
        #pragma unroll
        for (int a = 0; a < A_; a++) {
            uint2 u = *(const uint2*)&sl[(a*8 + r)*128 + kkg];
            va[a][0] = __uint_as_float(u.x << 16);
            va[a][1] = __uint_as_float(u.x & 0xffff0000u);
            va[a][2] = __uint_as_float(u.y << 16);
            va[a][3] = __uint_as_float(u.y & 0xffff0000u);
        }
        #pragma unroll
        for (int h = 0; h < H_; h++) {
            float m0 = soft_s[h][0]*va[0][0];
            float m1 = soft_s[h][0]*va[0][1];
            float m2 = soft_s[h][0]*va[0][2];
            float m3 = soft_s[h][0]*va[0][3];
            #pragma unroll
            for (int a = 1; a < A_; a++) {
                m0 += soft_s[h][a]*va[a][0];
                m1 += soft_s[h][a]*va[a][1];
                m2 += soft_s[h][a]*va[a][2];
                m3 += soft_s[h][a]*va[a][3];
            }
            uint2 w;
            w.x = pack2_bf(m0, m1);
            w.y = pack2_bf(m2, m3);
            *(uint2*)&Msb[h*MH_ + r*MR_ + kkg] = w;
        }
    }
    __syncthreads();

    // ---- compute phase ----
    int lane = tid & 63;
    int head = (tid >> 6) * 2 + (lane >> 5);
    int e    = lane & 7;
    int rsub = (lane >> 3) & 3;
    int col  = head*32 + e*4;
    int kbase = ks*KSL_ + rsub*32;

    float acc[8][4];
    #pragma unroll
    for (int r = 0; r < 8; r++)
        #pragma unroll
        for (int c = 0; c < 4; c++) acc[r][c] = 0.0f;

    const float* Tin_b = Tin + (size_t)b*N_*D_;
    const ushort* msb  = &Msb[head*MH_ + rsub*32];

    #pragma unroll 2
    for (int kt = 0; kt < 8; kt++) {
        int kr = kbase + kt*4;
        float4 t0 = *(const float4*)&Tin_b[(size_t)(kr+0)*D_ + col];
        float4 t1 = *(const float4*)&Tin_b[(size_t)(kr+1)*D_ + col];
        float4 t2 = *(const float4*)&Tin_b[(size_t)(kr+2)*D_ + col];
        float4 t3 = *(const float4*)&Tin_b[(size_t)(kr+3)*D_ + col];
        #pragma unroll
        for (int r = 0; r < 8; r++) {
            uint2 mu = *(const uint2*)&msb[r*MR_ + kt*4];
            float m0 = __uint_as_float(mu.x << 16);
            float m1 = __uint_as_float(mu.x & 0xffff0000u);
            float m2 = __uint_as_float(mu.y << 16);
            float m3 = __uint_as_float(mu.y & 0xffff0000u);
            acc[r][0] += m0*t0.x + m1*t1.x + m2*t2.x + m3*t3.x;
            acc[r][1] += m0*t0.y + m1*t1.y + m2*t2.y + m3*t3.y;
            acc[r][2] += m0*t0.z + m1*t1.z + m2*t2.z + m3*t3.z;
            acc[r][3] += m0*t0.w + m1*t1.w + m2*t2.w + m3*t3.w;
        }
    }

    // ---- cross-rsub k-partial reduction: butterfly over lane bits 3,4 ----
    #pragma unroll
    for (int r = 0; r < 8; r++)
        #pragma unroll
        for (int c = 0; c < 4; c++) {
            float v = acc[r][c];
            v += __shfl_xor(v, 8);
            v += __shfl_xor(v, 16);
            acc[r][c] = v;
        }

    // each lane writes rows (rsub*2, rsub*2+1); static selection to keep acc in registers
    float4 oA = (rsub == 0) ? make_float4(acc[0][0], acc[0][1], acc[0][2], acc[0][3])
              : (rsub == 1) ? make_float4(acc[2][0], acc[2][1], acc[2][2], acc[2][3])
              : (rsub == 2) ? make_float4(acc[4][0], acc[4][1], acc[4][2], acc[4][3])
                            : make_float4(acc[6][0], acc[6][1], acc[6][2], acc[6][3]);
    float4 oB = (rsub == 0) ? make_float4(acc[1][0], acc[1][1], acc[1][2], acc[1][3])
              : (rsub == 1) ? make_float4(acc[3][0], acc[3][1], acc[3][2], acc[3][3])
              : (rsub == 2) ? make_float4(acc[5][0], acc[5][1], acc[5][2], acc[5][3])
                            : make_float4(acc[7][0], acc[7][1], acc[7][2], acc[7][3]);

    size_t outbase = ((size_t)ks*ROWS_ + (size_t)b*N_)*D_;
    int r0 = rsub*2;
    *(float4*)&Pp[outbase + (size_t)(n0+r0+0)*D_ + col] = oA;
    *(float4*)&Pp[outbase + (size_t)(n0+r0+1)*D_ + col] = oB;
}

// ---------------- reduce the KS_ partial slabs; apply inv-degree scale on step 0 -------------
__global__ void chain_reduce(const float* __restrict__ Pp, float* __restrict__ Tout,
                             const float* __restrict__ invd, int step)
{
    int idx = blockIdx.x * 256 + threadIdx.x;      // one float4 per thread
    int row = idx / (D_/4);
    int c4  = (idx % (D_/4)) * 4;
    float4 s = make_float4(0.f, 0.f, 0.f, 0.f);
    #pragma unroll
    for (int ks = 0; ks < KS_; ks++) {
        float4 v = *(const float4*)&Pp[((size_t)ks*ROWS_ + row)*D_ + c4];
        s.x += v.x; s.y += v.y; s.z += v.z; s.w += v.w;
    }
    float scale = (step == 0) ? invd[row] : 1.0f;
    s.x *= scale; s.y *= scale; s.z *= scale; s.w *= scale;
    *(float4*)&Tout[(size_t)row*D_ + c4] = s;
}

// ---------------- generic 64x64-tile SIMT GEMM, 4x4 microtile ----------------
// MODE 0: C = A @ Wv(cat) + Bv     MODE 1: C = A @ B + add
// MODE 2: C = gelu_exact(A @ B + bias)   MODE 3: C = A @ B + bias + add
#define BK 16
template<int MODE>
__global__ void gemm_kernel(const float* __restrict__ A, const float* __restrict__ Bm,
                            const float* __restrict__ bias, const float* __restrict__ add,
                            float* __restrict__ C, int M, int Ncols, int K)
{
    __shared__ __align__(16) float As[BK][68];
    __shared__ __align__(16) float Bs[BK][68];
    int m0 = blockIdx.x * 64;
    int n0 = blockIdx.y * 64;
    int tid = threadIdx.x;
    int tx = tid & 15, ty = tid >> 4;

    float acc[4][4];
    #pragma unroll
    for (int i = 0; i < 4; i++)
        #pragma unroll
        for (int j = 0; j < 4; j++) acc[i][j] = 0.0f;

    for (int k0 = 0; k0 < K; k0 += BK) {
        {
            int m = tid >> 2;
            int k = (tid & 3) * 4;
            float4 v = *(const float4*)&A[(size_t)(m0+m)*K + k0 + k];
            As[k+0][m] = v.x; As[k+1][m] = v.y; As[k+2][m] = v.z; As[k+3][m] = v.w;
        }
        {
            int k = tid >> 4;
            int n = (tid & 15) * 4;
            float4 v;
            if constexpr (MODE == 0) {
                int c = n0 + n; int h = c >> 5; int ee = c & 31;
                v = *(const float4*)&Bm[(size_t)h*D_*DH_ + (size_t)(k0+k)*DH_ + ee];
            } else {
                v = *(const float4*)&Bm[(size_t)(k0+k)*Ncols + n0 + n];
            }
            *(float4*)&Bs[k][n] = v;
        }
        __syncthreads();
        #pragma unroll
        for (int k = 0; k < BK; k++) {
            float4 a4 = *(const float4*)&As[k][ty*4];
            float4 b4 = *(const float4*)&Bs[k][tx*4];
            acc[0][0] += a4.x*b4.x; acc[0][1] += a4.x*b4.y; acc[0][2] += a4.x*b4.z; acc[0][3] += a4.x*b4.w;
            acc[1][0] += a4.y*b4.x; acc[1][1] += a4.y*b4.y; acc[1][2] += a4.y*b4.z; acc[1][3] += a4.y*b4.w;
            acc[2][0] += a4.z*b4.x; acc[2][1] += a4.z*b4.y; acc[2][2] += a4.z*b4.z; acc[2][3] += a4.z*b4.w;
            acc[3][0] += a4.w*b4.x; acc[3][1] += a4.w*b4.y; acc[3][2] += a4.w*b4.z; acc[3][3] += a4.w*b4.w;
        }
        __syncthreads();
    }

    #pragma unroll
    for (int i = 0; i < 4; i++) {
        int row  = m0 + ty*4 + i;
        int nloc = n0 + tx*4;
        float o[4];
        #pragma unroll
        for (int j = 0; j < 4; j++) {
            float v = acc[i][j];
            int c = nloc + j;
            if constexpr (MODE == 0) {
                int h = c >> 5, ee = c & 31, n = row & (N_-1);
                v += bias[(size_t)h*N_*DH_ + (size_t)n*DH_ + ee];
            }
            if constexpr (MODE == 1) {
                v += add[(size_t)row*Ncols + c];
            }
            if constexpr (MODE == 2) {
                v += bias[c];
                v = 0.5f * v * (1.0f + erff(v * 0.70710678118654752f));
            }
            if constexpr (MODE == 3) {
                v += bias[c] + add[(size_t)row*Ncols + c];
            }
            o[j] = v;
        }
        float4 ov = make_float4(o[0], o[1], o[2], o[3]);
        *(float4*)&C[(size_t)row*Ncols + nloc] = ov;
    }
}

// ---------------- layernorm over last dim W (256 or 512), one row per block ----------------
__global__ void ln_kernel(const float* __restrict__ in, float* __restrict__ out,
                          const float* __restrict__ g, const float* __restrict__ bta, int W)
{
    __shared__ float row[512];
    __shared__ float red[256];
    int r = blockIdx.x;
    int tid = threadIdx.x;
    const float* ip = in + (size_t)r * W;

    float local = 0.0f;
    for (int i = tid; i < W; i += 256) { float v = ip[i]; row[i] = v; local += v; }
    red[tid] = local;
    __syncthreads();
    for (int s = 128; s > 0; s >>= 1) {
        if (tid < s) red[tid] += red[tid + s];
        __syncthreads();
    }
    float mean = red[0] / (float)W;
    __syncthreads();

    float lv = 0.0f;
    for (int i = tid; i < W; i += 256) { float d = row[i] - mean; lv += d*d; }
    red[tid] = lv;
    __syncthreads();
    for (int s = 128; s > 0; s >>= 1) {
        if (tid < s) red[tid] += red[tid + s];
        __syncthreads();
    }
    float var = red[0] / (float)W;
    float rstd = 1.0f / sqrtf(var + 1e-12f);

    float* op = out + (size_t)r * W;
    for (int i = tid; i < W; i += 256) op[i] = (row[i] - mean) * rstd * g[i] + bta[i];
}

extern "C" void kernel_launch(void* const* d_in, const int* in_sizes, int n_in,
                              void* d_out, int out_size, void* d_ws, size_t ws_size,
                              hipStream_t stream)
{
    const float* adj    = (const float*)d_in[0];
    const float* degree = (const float*)d_in[1];
    const float* x      = (const float*)d_in[2];
    const float* kern   = (const float*)d_in[3];
    const float* Wv     = (const float*)d_in[4];
    const float* Bv     = (const float*)d_in[5];
    const float* W0     = (const float*)d_in[6];
    const float* gamma2 = (const float*)d_in[7];
    const float* beta2  = (const float*)d_in[8];
    const float* W1     = (const float*)d_in[9];
    const float* b1     = (const float*)d_in[10];
    const float* gf     = (const float*)d_in[11];
    const float* bf_    = (const float*)d_in[12];
    const float* W2     = (const float*)d_in[13];
    const float* b2f    = (const float*)d_in[14];
    float* out = (float*)d_out;
    float* ws  = (float*)d_ws;

    // ws layout (float units)
    size_t off = 0;
    float* soft  = ws + off; off += 512;
    float* invd  = ws + off; off += 2048;
    float* T0    = ws + off; off += (size_t)ROWS_*D_;
    float* T1    = ws + off; off += (size_t)ROWS_*D_;
    float* resid = ws + off; off += (size_t)ROWS_*D_;
    float* hbuf  = ws + off; off += (size_t)ROWS_*D_;
    float* fbuf  = ws + off; off += (size_t)ROWS_*2*D_;
    float* fbuf2 = ws + off; off += (size_t)ROWS_*2*D_;
    float* Pp    = ws + off; off += (size_t)KS_*ROWS_*D_;
    ushort* adjp = (ushort*)(ws + off);   // ADJ_ELEMS_ bf16 = 37.75 MB

    // 1) soft weights + inverse degree diag
    prep_kernel<<<9, 256, 0, stream>>>(kern, degree, soft, invd);
    // 1b) pack adjacency into bf16 block-consumption order
    adj_pack_kernel<<<(int)(ADJ_ELEMS_/8/256), 256, 0, stream>>>(adj, adjp);
    // 2) V = x @ Wv (+Bv), concat layout [B*N][256] col = h*32+e
    gemm_kernel<0><<<dim3(ROWS_/64, D_/64), 256, 0, stream>>>(x, Wv, Bv, nullptr, T0, ROWS_, D_, D_);
    // 3) chain right-to-left with K-split partials + reduce; inv-degree scale on step 0
    int chain_grid  = B_*128*KS_;                    // 2048
    int reduce_grid = (ROWS_*D_/4) / 256;            // 512
    chain_kernel<<<chain_grid, 256, 0, stream>>>(adjp, soft, T0, Pp, 3);
    chain_reduce<<<reduce_grid, 256, 0, stream>>>(Pp, T1, invd, 3);
    chain_kernel<<<chain_grid, 256, 0, stream>>>(adjp, soft, T1, Pp, 2);
    chain_reduce<<<reduce_grid, 256, 0, stream>>>(Pp, T0, invd, 2);
    chain_kernel<<<chain_grid, 256, 0, stream>>>(adjp, soft, T0, Pp, 1);
    chain_reduce<<<reduce_grid, 256, 0, stream>>>(Pp, T1, invd, 1);
    chain_kernel<<<chain_grid, 256, 0, stream>>>(adjp, soft, T1, Pp, 0);
    chain_reduce<<<reduce_grid, 256, 0, stream>>>(Pp, T0, invd, 0);
    // 4) residual = attn @ W0 + x
    gemm_kernel<1><<<dim3(ROWS_/64, D_/64), 256, 0, stream>>>(T0, W0, nullptr, x, resid, ROWS_, D_, D_);
    // 5) h = LN(residual)
    ln_kernel<<<ROWS_, 256, 0, stream>>>(resid, hbuf, gamma2, beta2, D_);
    // 6) f = gelu(h @ W1 + b1)
    gemm_kernel<2><<<dim3(ROWS_/64, (2*D_)/64), 256, 0, stream>>>(hbuf, W1, b1, nullptr, fbuf, ROWS_, 2*D_, D_);
    // 7) f = LN(f)
    ln_kernel<<<ROWS_, 256, 0, stream>>>(fbuf, fbuf2, gf, bf_, 2*D_);
    // 8) out = f @ W2 + b2f + residual
    gemm_kernel<3><<<dim3(ROWS_/64, D_/64), 256, 0, stream>>>(fbuf2, W2, b2f, resid, out, ROWS_, D_, 2*D_);
}

// Round 6
// 201.475 us; speedup vs baseline: 3.1701x; 3.1701x over previous
//
#include <hip/hip_runtime.h>
#include <hip/hip_bf16.h>
#include <math.h>

#define B_ 2
#define A_ 9
#define N_ 1024
#define P_ 4
#define D_ 256
#define H_ 8
#define DH_ 32
#define ROWS_ (B_*N_)   // 2048
#define KS_ 8           // K-split factor for chain (k-slice 128)
#define ADJ_ELEMS_ ((size_t)B_*A_*N_*N_)
#define SLABF4_ 131072  // Pp slab stride in float4 (2*16*1024*16/4)

typedef __attribute__((ext_vector_type(8))) short bf16x8;
typedef __attribute__((ext_vector_type(4))) float f32x4;

__device__ __forceinline__ uint pack2_bf(float x, float y) {
    uint ux = __float_as_uint(x); ux += 0x7fffu + ((ux >> 16) & 1u);
    uint uy = __float_as_uint(y); uy += 0x7fffu + ((uy >> 16) & 1u);
    return (ux >> 16) | (uy & 0xffff0000u);
}
__device__ __forceinline__ float bflo(uint u){ return __uint_as_float(u << 16); }
__device__ __forceinline__ float bfhi(uint u){ return __uint_as_float(u & 0xffff0000u); }

// ---------------- prep: softmax(relu(kernels)) over A axis + 1/diag(degree) ----------------
__global__ void prep_kernel(const float* __restrict__ kernels, const float* __restrict__ degree,
                            float* __restrict__ soft, float* __restrict__ invd)
{
    int t = threadIdx.x;
    if (blockIdx.x == 0) {
        if (t < H_*P_) {
            int h = t >> 2, p = t & 3;
            float vals[A_];
            float m = 0.0f;
            #pragma unroll
            for (int a = 0; a < A_; a++) {
                float v = kernels[h*A_*P_ + a*P_ + p];
                v = v > 0.0f ? v : 0.0f;
                vals[a] = v;
                m = fmaxf(m, v);
            }
            float s = 0.0f;
            #pragma unroll
            for (int a = 0; a < A_; a++) { vals[a] = expf(vals[a] - m); s += vals[a]; }
            float inv = 1.0f / s;
            #pragma unroll
            for (int a = 0; a < A_; a++) soft[h*A_*P_ + a*P_ + p] = vals[a] * inv;
        }
    } else {
        int idx = (blockIdx.x - 1) * 256 + t;
        if (idx < ROWS_) {
            int b = idx >> 10, n = idx & (N_-1);
            invd[idx] = 1.0f / degree[(size_t)b*N_*N_ + (size_t)n*N_ + n];
        }
    }
}

// ---------------- pack adjacency fp32 -> bf16, per-chunk-contiguous block order ----------------
// dst: [b][rowblk(64)][ks(8)][chunk(4)][a(9)][r(16)][kk(32)] bf16; one uint4 (8 bf16) per thread.
__global__ void adj_pack_kernel(const float* __restrict__ in, ushort* __restrict__ out)
{
    int j = blockIdx.x * 256 + threadIdx.x;    // uint4 index over ADJ_ELEMS_/8
    int kk8   = j & 3;
    int r     = (j >> 2) & 15;
    int t     = j >> 6;
    int a     = t % 9;
    int rest  = t / 9;          // chunk + ks*4 + rowblk*32 + b*2048
    int chunk = rest & 3;
    int ks    = (rest >> 2) & 7;
    int rowblk= (rest >> 5) & 63;
    int b     = rest >> 11;
    const float* src = &in[(((size_t)b*A_ + a)*N_ + (rowblk*16 + r))*N_ + ks*128 + chunk*32 + kk8*8];
    float4 v0 = *(const float4*)src;
    float4 v1 = *(const float4*)(src + 4);
    uint4 o;
    o.x = pack2_bf(v0.x, v0.y);
    o.y = pack2_bf(v0.z, v0.w);
    o.z = pack2_bf(v1.x, v1.y);
    o.w = pack2_bf(v1.z, v1.w);
    ((uint4*)out)[j] = o;
}

// ---------------- MFMA chain step: Pp[ks] = M_step[:, ks-slice] @ T[ks-slice, :] ----------------
// grid = B*64*KS_ = 1024 blocks, 256 threads (4 waves). Block: 16 rows x 256 cols, k-depth 128.
// T stored as bf16 panels [b][cg(16)][k(1024)][cc(16)]. Per 32-k chunk: mix M (8 heads) into LDS
// (bf16, k-block XOR swizzle), transpose-stage T chunk into LDS [piece][c][k] (same swizzle),
// then each wave does 4 mfma_f32_16x16x32_bf16 (tiles cg = w+4j). Epilogue transposes acc via LDS
// so Pp global stores are 1KB-dense per 16 lanes (panel layout [ks][b][cg][n][cc] fp32).
__global__ __launch_bounds__(256, 4)
void chain_mfma(const ushort* __restrict__ adjp, const float* __restrict__ soft,
                const ushort* __restrict__ Tin, float* __restrict__ Pp, int step)
{
    __shared__ __align__(16) ushort smem[8*640 + 16*648];   // M: 8 heads x [16r][40k]; T: 16 pieces x [16c][40k] (+stagger)
    __shared__ float soft_s[8][9];
    ushort* sm_ms = smem;
    ushort* sm_t  = smem + 8*640;

    int bid    = blockIdx.x;
    int ks     = bid & (KS_-1);
    int rowblk = (bid >> 3) & 63;
    int b      = bid >> 9;
    int n0     = rowblk * 16;
    int tid    = threadIdx.x;
    int lane   = tid & 63;
    int w      = tid >> 6;

    if (tid < 72) { int h = tid/9, a = tid%9; soft_s[h][a] = soft[h*A_*P_ + a*P_ + step]; }
    __syncthreads();

    // mix mapping: r = tid>>4, k-pair = 2*(tid&15); swizzled k offset
    int mr   = tid >> 4;
    int mk2  = (tid & 15) * 2;
    int mk2s = mk2 ^ ((mr & 3) << 3);
    const ushort* ablk = adjp + (size_t)((b*64 + rowblk)*8 + ks) * 18432;

    // stage mapping: piece p = tid>>4, k-row pair k0 = 2*(tid&15)
    int sp  = tid >> 4;
    int sk0 = (tid & 15) * 2;
    const ushort* tbase = Tin + ((size_t)(b*16 + sp)*1024 + (size_t)ks*128) * 16;

    // compute mapping
    int g   = lane >> 4;
    int c15 = lane & 15;
    int gx  = (g ^ (c15 & 3)) * 8;   // swizzled k-block offset (ushorts)

    f32x4 acc[4];
    #pragma unroll
    for (int j = 0; j < 4; j++) acc[j] = (f32x4){0.f, 0.f, 0.f, 0.f};

    for (int chunk = 0; chunk < 4; chunk++) {
        // ---- issue global loads first (don't touch LDS) ----
        uint av[9];
        {
            const ushort* asl = ablk + chunk*4608 + mk2;
            #pragma unroll
            for (int a = 0; a < A_; a++) av[a] = *(const uint*)&asl[(a*16 + mr)*32];
        }
        const ushort* tsl = tbase + (size_t)(chunk*32 + sk0) * 16;
        uint4 q0 = *(const uint4*)(tsl + 0);     // row k0,  c 0..7
        uint4 q1 = *(const uint4*)(tsl + 8);     // row k0,  c 8..15
        uint4 q2 = *(const uint4*)(tsl + 16);    // row k0+1,c 0..7
        uint4 q3 = *(const uint4*)(tsl + 24);    // row k0+1,c 8..15

        if (chunk) __syncthreads();   // previous compute must be done before overwriting LDS

        // ---- mix all 8 heads into sm_ms ----
        {
            float va0[9], va1[9];
            #pragma unroll
            for (int a = 0; a < A_; a++) { va0[a] = bflo(av[a]); va1[a] = bfhi(av[a]); }
            #pragma unroll
            for (int h = 0; h < H_; h++) {
                float s0 = soft_s[h][0]*va0[0];
                float s1 = soft_s[h][0]*va1[0];
                #pragma unroll
                for (int a = 1; a < A_; a++) { s0 += soft_s[h][a]*va0[a]; s1 += soft_s[h][a]*va1[a]; }
                *(uint*)&sm_ms[h*640 + mr*40 + mk2s] = pack2_bf(s0, s1);
            }
        }
        // ---- transpose-stage T chunk into sm_t: [piece][c(16)][k(32)+swz] ----
        {
            uint l0[4] = {q0.x, q0.y, q0.z, q0.w};
            uint l1[4] = {q1.x, q1.y, q1.z, q1.w};
            uint h0[4] = {q2.x, q2.y, q2.z, q2.w};
            uint h1[4] = {q3.x, q3.y, q3.z, q3.w};
            #pragma unroll
            for (int ci = 0; ci < 8; ci++) {
                uint a0 = (l0[ci>>1] >> ((ci&1)*16)) & 0xffffu;
                uint b0 = (h0[ci>>1] >> ((ci&1)*16)) & 0xffffu;
                int k0s = sk0 ^ ((ci & 3) << 3);
                *(uint*)&sm_t[sp*648 + ci*40 + k0s] = a0 | (b0 << 16);
            }
            #pragma unroll
            for (int ci = 0; ci < 8; ci++) {
                int c = ci + 8;
                uint a0 = (l1[ci>>1] >> ((ci&1)*16)) & 0xffffu;
                uint b0 = (h1[ci>>1] >> ((ci&1)*16)) & 0xffffu;
                int k0s = sk0 ^ ((c & 3) << 3);
                *(uint*)&sm_t[sp*648 + c*40 + k0s] = a0 | (b0 << 16);
            }
        }
        __syncthreads();

        // ---- MFMA: wave w computes tiles cg = w, w+4, w+8, w+12 ----
        {
            const ushort* mb = sm_ms + c15*40 + gx;
            const ushort* tb = sm_t  + c15*40 + gx;
            #pragma unroll
            for (int j = 0; j < 4; j++) {
                int cg = w + 4*j;
                int h  = cg >> 1;
                bf16x8 af  = *(const bf16x8*)&mb[h*640];
                bf16x8 bfr = *(const bf16x8*)&tb[cg*648];
                acc[j] = __builtin_amdgcn_mfma_f32_16x16x32_bf16(af, bfr, acc[j], 0, 0, 0);
            }
        }
    }

    // ---- epilogue: transpose acc via LDS, then 1KB-dense panel stores ----
    __syncthreads();
    float* Ep = (float*)smem;   // 16 pieces x 16r x 16c fp32 = 16KB (aliases mix/stage buffers)
    #pragma unroll
    for (int j = 0; j < 4; j++) {
        int cg = w + 4*j;
        #pragma unroll
        for (int i = 0; i < 4; i++)
            Ep[cg*256 + (g*4 + i)*16 + c15] = acc[j][i];   // C/D: col=lane&15, row=(lane>>4)*4+reg
    }
    __syncthreads();
    {
        int p = tid >> 4, r = tid & 15;
        float* dst = Pp + (((size_t)(ks*B_ + b)*16 + p)*N_ + (n0 + r)) * 16;
        const float* src = &Ep[p*256 + r*16];
        *(float4*)&dst[0]  = *(const float4*)&src[0];
        *(float4*)&dst[4]  = *(const float4*)&src[4];
        *(float4*)&dst[8]  = *(const float4*)&src[8];
        *(float4*)&dst[12] = *(const float4*)&src[12];
    }
}

// ---------------- reduce KS_ slabs (panel fp32). FINAL=0: bf16 panels. FINAL=1: fp32 rows + invd ----
template<int FINAL>
__global__ void chain_reduce(const float* __restrict__ Pp, void* __restrict__ outp,
                             const float* __restrict__ invd)
{
    int pidx = blockIdx.x * 256 + threadIdx.x;      // one float4 per thread
    float4 s = make_float4(0.f, 0.f, 0.f, 0.f);
    #pragma unroll
    for (int ks = 0; ks < KS_; ks++) {
        float4 v = ((const float4*)Pp)[(size_t)ks*SLABF4_ + pidx];
        s.x += v.x; s.y += v.y; s.z += v.z; s.w += v.w;
    }
    if constexpr (FINAL) {
        int lin = pidx * 4;
        int cc = lin & 15;
        int n  = (lin >> 4) & (N_-1);
        int cg = (lin >> 14) & 15;
        int b  = lin >> 18;
        float sc = invd[b*N_ + n];
        float4 o = make_float4(s.x*sc, s.y*sc, s.z*sc, s.w*sc);
        *(float4*)&((float*)outp)[((size_t)(b*N_ + n))*D_ + cg*16 + cc] = o;
    } else {
        uint2 wv;
        wv.x = pack2_bf(s.x, s.y);
        wv.y = pack2_bf(s.z, s.w);
        ((uint2*)outp)[pidx] = wv;
    }
}

// ---------------- generic 64x64-tile SIMT GEMM, 4x4 microtile ----------------
// MODE 0: T = x @ Wv(cat) + Bv  -> bf16 panels     MODE 1: C = A @ B + add
// MODE 2: C = gelu_exact(A @ B + bias)             MODE 3: C = A @ B + bias + add
#define BK 16
template<int MODE>
__global__ void gemm_kernel(const float* __restrict__ A, const float* __restrict__ Bm,
                            const float* __restrict__ bias, const float* __restrict__ add,
                            float* __restrict__ C, int M, int Ncols, int K)
{
    __shared__ __align__(16) float As[BK][68];
    __shared__ __align__(16) float Bs[BK][68];
    int m0 = blockIdx.x * 64;
    int n0 = blockIdx.y * 64;
    int tid = threadIdx.x;
    int tx = tid & 15, ty = tid >> 4;

    float acc[4][4];
    #pragma unroll
    for (int i = 0; i < 4; i++)
        #pragma unroll
        for (int j = 0; j < 4; j++) acc[i][j] = 0.0f;

    for (int k0 = 0; k0 < K; k0 += BK) {
        {
            int m = tid >> 2;
            int k = (tid & 3) * 4;
            float4 v = *(const float4*)&A[(size_t)(m0+m)*K + k0 + k];
            As[k+0][m] = v.x; As[k+1][m] = v.y; As[k+2][m] = v.z; As[k+3][m] = v.w;
        }
        {
            int k = tid >> 4;
            int n = (tid & 15) * 4;
            float4 v;
            if constexpr (MODE == 0) {
                int c = n0 + n; int h = c >> 5; int ee = c & 31;
                v = *(const float4*)&Bm[(size_t)h*D_*DH_ + (size_t)(k0+k)*DH_ + ee];
            } else {
                v = *(const float4*)&Bm[(size_t)(k0+k)*Ncols + n0 + n];
            }
            *(float4*)&Bs[k][n] = v;
        }
        __syncthreads();
        #pragma unroll
        for (int k = 0; k < BK; k++) {
            float4 a4 = *(const float4*)&As[k][ty*4];
            float4 b4 = *(const float4*)&Bs[k][tx*4];
            acc[0][0] += a4.x*b4.x; acc[0][1] += a4.x*b4.y; acc[0][2] += a4.x*b4.z; acc[0][3] += a4.x*b4.w;
            acc[1][0] += a4.y*b4.x; acc[1][1] += a4.y*b4.y; acc[1][2] += a4.y*b4.z; acc[1][3] += a4.y*b4.w;
            acc[2][0] += a4.z*b4.x; acc[2][1] += a4.z*b4.y; acc[2][2] += a4.z*b4.z; acc[2][3] += a4.z*b4.w;
            acc[3][0] += a4.w*b4.x; acc[3][1] += a4.w*b4.y; acc[3][2] += a4.w*b4.z; acc[3][3] += a4.w*b4.w;
        }
        __syncthreads();
    }

    #pragma unroll
    for (int i = 0; i < 4; i++) {
        int row  = m0 + ty*4 + i;
        int nloc = n0 + tx*4;
        float o[4];
        #pragma unroll
        for (int j = 0; j < 4; j++) {
            float v = acc[i][j];
            int c = nloc + j;
            if constexpr (MODE == 0) {
                int h = c >> 5, ee = c & 31, n = row & (N_-1);
                v += bias[(size_t)h*N_*DH_ + (size_t)n*DH_ + ee];
            }
            if constexpr (MODE == 1) {
                v += add[(size_t)row*Ncols + c];
            }
            if constexpr (MODE == 2) {
                v += bias[c];
                v = 0.5f * v * (1.0f + erff(v * 0.70710678118654752f));
            }
            if constexpr (MODE == 3) {
                v += bias[c] + add[(size_t)row*Ncols + c];
            }
            o[j] = v;
        }
        if constexpr (MODE == 0) {
            // write bf16 panels [b][cg][n][cc]
            int bb = row >> 10, n = row & (N_-1);
            int cg = nloc >> 4, cc = nloc & 15;
            uint2 wv;
            wv.x = pack2_bf(o[0], o[1]);
            wv.y = pack2_bf(o[2], o[3]);
            *(uint2*)&((ushort*)C)[(((size_t)bb*16 + cg)*N_ + n)*16 + cc] = wv;
        } else {
            float4 ov = make_float4(o[0], o[1], o[2], o[3]);
            *(float4*)&C[(size_t)row*Ncols + nloc] = ov;
        }
    }
}

// ---------------- layernorm over last dim W (256 or 512), one row per block ----------------
__global__ void ln_kernel(const float* __restrict__ in, float* __restrict__ out,
                          const float* __restrict__ g, const float* __restrict__ bta, int W)
{
    __shared__ float row[512];
    __shared__ float red[256];
    int r = blockIdx.x;
    int tid = threadIdx.x;
    const float* ip = in + (size_t)r * W;

    float local = 0.0f;
    for (int i = tid; i < W; i += 256) { float v = ip[i]; row[i] = v; local += v; }
    red[tid] = local;
    __syncthreads();
    for (int s = 128; s > 0; s >>= 1) {
        if (tid < s) red[tid] += red[tid + s];
        __syncthreads();
    }
    float mean = red[0] / (float)W;
    __syncthreads();

    float lv = 0.0f;
    for (int i = tid; i < W; i += 256) { float d = row[i] - mean; lv += d*d; }
    red[tid] = lv;
    __syncthreads();
    for (int s = 128; s > 0; s >>= 1) {
        if (tid < s) red[tid] += red[tid + s];
        __syncthreads();
    }
    float var = red[0] / (float)W;
    float rstd = 1.0f / sqrtf(var + 1e-12f);

    float* op = out + (size_t)r * W;
    for (int i = tid; i < W; i += 256) op[i] = (row[i] - mean) * rstd * g[i] + bta[i];
}

extern "C" void kernel_launch(void* const* d_in, const int* in_sizes, int n_in,
                              void* d_out, int out_size, void* d_ws, size_t ws_size,
                              hipStream_t stream)
{
    const float* adj    = (const float*)d_in[0];
    const float* degree = (const float*)d_in[1];
    const float* x      = (const float*)d_in[2];
    const float* kern   = (const float*)d_in[3];
    const float* Wv     = (const float*)d_in[4];
    const float* Bv     = (const float*)d_in[5];
    const float* W0     = (const float*)d_in[6];
    const float* gamma2 = (const float*)d_in[7];
    const float* beta2  = (const float*)d_in[8];
    const float* W1     = (const float*)d_in[9];
    const float* b1     = (const float*)d_in[10];
    const float* gf     = (const float*)d_in[11];
    const float* bf_    = (const float*)d_in[12];
    const float* W2     = (const float*)d_in[13];
    const float* b2f    = (const float*)d_in[14];
    float* out = (float*)d_out;
    float* ws  = (float*)d_ws;

    // ws layout (float units) — same slots as R4
    size_t off = 0;
    float* soft  = ws + off; off += 512;
    float* invd  = ws + off; off += 2048;
    float* T0    = ws + off; off += (size_t)ROWS_*D_;     // bf16 panels (1MB) or fp32 attn (2MB)
    float* T1    = ws + off; off += (size_t)ROWS_*D_;     // bf16 panels
    float* resid = ws + off; off += (size_t)ROWS_*D_;
    float* hbuf  = ws + off; off += (size_t)ROWS_*D_;
    float* fbuf  = ws + off; off += (size_t)ROWS_*2*D_;
    float* fbuf2 = ws + off; off += (size_t)ROWS_*2*D_;
    float* Pp    = ws + off; off += (size_t)KS_*ROWS_*D_; // fp32 panels, 16.8MB
    ushort* adjp = (ushort*)(ws + off);                   // 37.75 MB

    ushort* T0b = (ushort*)T0;
    ushort* T1b = (ushort*)T1;
    float*  attn = T0;    // reduce<1> output (fp32 row-major), reuses T0 slot

    // 1) soft weights + inverse degree diag
    prep_kernel<<<9, 256, 0, stream>>>(kern, degree, soft, invd);
    // 1b) pack adjacency into bf16 per-chunk-contiguous block order
    adj_pack_kernel<<<(int)(ADJ_ELEMS_/8/256), 256, 0, stream>>>(adj, adjp);
    // 2) V = x @ Wv (+Bv) -> bf16 panels in T0
    gemm_kernel<0><<<dim3(ROWS_/64, D_/64), 256, 0, stream>>>(x, Wv, Bv, nullptr, T0, ROWS_, D_, D_);
    // 3) chain right-to-left, MFMA, K-split partials + reduce; inv-degree on last step
    int chain_grid  = B_*64*KS_;    // 1024
    int reduce_grid = SLABF4_/256;  // 512
    chain_mfma<<<chain_grid, 256, 0, stream>>>(adjp, soft, T0b, Pp, 3);
    chain_reduce<0><<<reduce_grid, 256, 0, stream>>>(Pp, T1b, invd);
    chain_mfma<<<chain_grid, 256, 0, stream>>>(adjp, soft, T1b, Pp, 2);
    chain_reduce<0><<<reduce_grid, 256, 0, stream>>>(Pp, T0b, invd);
    chain_mfma<<<chain_grid, 256, 0, stream>>>(adjp, soft, T0b, Pp, 1);
    chain_reduce<0><<<reduce_grid, 256, 0, stream>>>(Pp, T1b, invd);
    chain_mfma<<<chain_grid, 256, 0, stream>>>(adjp, soft, T1b, Pp, 0);
    chain_reduce<1><<<reduce_grid, 256, 0, stream>>>(Pp, attn, invd);
    // 4) residual = attn @ W0 + x
    gemm_kernel<1><<<dim3(ROWS_/64, D_/64), 256, 0, stream>>>(attn, W0, nullptr, x, resid, ROWS_, D_, D_);
    // 5) h = LN(residual)
    ln_kernel<<<ROWS_, 256, 0, stream>>>(resid, hbuf, gamma2, beta2, D_);
    // 6) f = gelu(h @ W1 + b1)
    gemm_kernel<2><<<dim3(ROWS_/64, (2*D_)/64), 256, 0, stream>>>(hbuf, W1, b1, nullptr, fbuf, ROWS_, 2*D_, D_);
    // 7) f = LN(f)
    ln_kernel<<<ROWS_, 256, 0, stream>>>(fbuf, fbuf2, gf, bf_, 2*D_);
    // 8) out = f @ W2 + b2f + residual
    gemm_kernel<3><<<dim3(ROWS_/64, D_/64), 256, 0, stream>>>(fbuf2, W2, b2f, resid, out, ROWS_, D_, 2*D_);
}

// Round 8
// 200.547 us; speedup vs baseline: 3.1847x; 1.0046x over previous
//
#include <hip/hip_runtime.h>
#include <hip/hip_bf16.h>
#include <math.h>

#define B_ 2
#define A_ 9
#define N_ 1024
#define P_ 4
#define D_ 256
#define H_ 8
#define DH_ 32
#define ROWS_ (B_*N_)   // 2048
#define KS_ 8           // K-split factor for chain (k-slice 128)
#define ADJ_ELEMS_ ((size_t)B_*A_*N_*N_)
#define SLABF4_ 131072  // Pp slab stride in float4 (2*16*1024*16/4)

typedef __attribute__((ext_vector_type(8))) short bf16x8;
typedef __attribute__((ext_vector_type(4))) float f32x4;

__device__ __forceinline__ uint pack2_bf(float x, float y) {
    uint ux = __float_as_uint(x); ux += 0x7fffu + ((ux >> 16) & 1u);
    uint uy = __float_as_uint(y); uy += 0x7fffu + ((uy >> 16) & 1u);
    return (ux >> 16) | (uy & 0xffff0000u);
}
__device__ __forceinline__ float bflo(uint u){ return __uint_as_float(u << 16); }
__device__ __forceinline__ float bfhi(uint u){ return __uint_as_float(u & 0xffff0000u); }

// ---------------- prep ----------------
__global__ void prep_kernel(const float* __restrict__ kernels, const float* __restrict__ degree,
                            float* __restrict__ soft, float* __restrict__ invd)
{
    int t = threadIdx.x;
    if (blockIdx.x == 0) {
        if (t < H_*P_) {
            int h = t >> 2, p = t & 3;
            float vals[A_];
            float m = 0.0f;
            #pragma unroll
            for (int a = 0; a < A_; a++) {
                float v = kernels[h*A_*P_ + a*P_ + p];
                v = v > 0.0f ? v : 0.0f;
                vals[a] = v;
                m = fmaxf(m, v);
            }
            float s = 0.0f;
            #pragma unroll
            for (int a = 0; a < A_; a++) { vals[a] = expf(vals[a] - m); s += vals[a]; }
            float inv = 1.0f / s;
            #pragma unroll
            for (int a = 0; a < A_; a++) soft[h*A_*P_ + a*P_ + p] = vals[a] * inv;
        }
    } else {
        int idx = (blockIdx.x - 1) * 256 + t;
        if (idx < ROWS_) {
            int b = idx >> 10, n = idx & (N_-1);
            invd[idx] = 1.0f / degree[(size_t)b*N_*N_ + (size_t)n*N_ + n];
        }
    }
}

// ---------------- pack adjacency fp32 -> bf16, per-chunk-contiguous block order ----------------
__global__ void adj_pack_kernel(const float* __restrict__ in, ushort* __restrict__ out)
{
    int j = blockIdx.x * 256 + threadIdx.x;
    int kk8   = j & 3;
    int r     = (j >> 2) & 15;
    int t     = j >> 6;
    int a     = t % 9;
    int rest  = t / 9;
    int chunk = rest & 3;
    int ks    = (rest >> 2) & 7;
    int rowblk= (rest >> 5) & 63;
    int b     = rest >> 11;
    const float* src = &in[(((size_t)b*A_ + a)*N_ + (rowblk*16 + r))*N_ + ks*128 + chunk*32 + kk8*8];
    float4 v0 = *(const float4*)src;
    float4 v1 = *(const float4*)(src + 4);
    uint4 o;
    o.x = pack2_bf(v0.x, v0.y);
    o.y = pack2_bf(v0.z, v0.w);
    o.z = pack2_bf(v1.x, v1.y);
    o.w = pack2_bf(v1.z, v1.w);
    ((uint4*)out)[j] = o;
}

// ---------------- MFMA chain step (verified R6) ----------------
__global__ __launch_bounds__(256, 4)
void chain_mfma(const ushort* __restrict__ adjp, const float* __restrict__ soft,
                const ushort* __restrict__ Tin, float* __restrict__ Pp, int step)
{
    __shared__ __align__(16) ushort smem[8*640 + 16*648];
    __shared__ float soft_s[8][9];
    ushort* sm_ms = smem;
    ushort* sm_t  = smem + 8*640;

    int bid    = blockIdx.x;
    int ks     = bid & (KS_-1);
    int rowblk = (bid >> 3) & 63;
    int b      = bid >> 9;
    int n0     = rowblk * 16;
    int tid    = threadIdx.x;
    int lane   = tid & 63;
    int w      = tid >> 6;

    if (tid < 72) { int h = tid/9, a = tid%9; soft_s[h][a] = soft[h*A_*P_ + a*P_ + step]; }
    __syncthreads();

    int mr   = tid >> 4;
    int mk2  = (tid & 15) * 2;
    int mk2s = mk2 ^ ((mr & 3) << 3);
    const ushort* ablk = adjp + (size_t)((b*64 + rowblk)*8 + ks) * 18432;

    int sp  = tid >> 4;
    int sk0 = (tid & 15) * 2;
    const ushort* tbase = Tin + ((size_t)(b*16 + sp)*1024 + (size_t)ks*128) * 16;

    int g   = lane >> 4;
    int c15 = lane & 15;
    int gx  = (g ^ (c15 & 3)) * 8;

    f32x4 acc[4];
    #pragma unroll
    for (int j = 0; j < 4; j++) acc[j] = (f32x4){0.f, 0.f, 0.f, 0.f};

    for (int chunk = 0; chunk < 4; chunk++) {
        uint av[9];
        {
            const ushort* asl = ablk + chunk*4608 + mk2;
            #pragma unroll
            for (int a = 0; a < A_; a++) av[a] = *(const uint*)&asl[(a*16 + mr)*32];
        }
        const ushort* tsl = tbase + (size_t)(chunk*32 + sk0) * 16;
        uint4 q0 = *(const uint4*)(tsl + 0);
        uint4 q1 = *(const uint4*)(tsl + 8);
        uint4 q2 = *(const uint4*)(tsl + 16);
        uint4 q3 = *(const uint4*)(tsl + 24);

        if (chunk) __syncthreads();

        {
            float va0[9], va1[9];
            #pragma unroll
            for (int a = 0; a < A_; a++) { va0[a] = bflo(av[a]); va1[a] = bfhi(av[a]); }
            #pragma unroll
            for (int h = 0; h < H_; h++) {
                float s0 = soft_s[h][0]*va0[0];
                float s1 = soft_s[h][0]*va1[0];
                #pragma unroll
                for (int a = 1; a < A_; a++) { s0 += soft_s[h][a]*va0[a]; s1 += soft_s[h][a]*va1[a]; }
                *(uint*)&sm_ms[h*640 + mr*40 + mk2s] = pack2_bf(s0, s1);
            }
        }
        {
            uint l0[4] = {q0.x, q0.y, q0.z, q0.w};
            uint l1[4] = {q1.x, q1.y, q1.z, q1.w};
            uint h0[4] = {q2.x, q2.y, q2.z, q2.w};
            uint h1[4] = {q3.x, q3.y, q3.z, q3.w};
            #pragma unroll
            for (int ci = 0; ci < 8; ci++) {
                uint a0 = (l0[ci>>1] >> ((ci&1)*16)) & 0xffffu;
                uint b0 = (h0[ci>>1] >> ((ci&1)*16)) & 0xffffu;
                int k0s = sk0 ^ ((ci & 3) << 3);
                *(uint*)&sm_t[sp*648 + ci*40 + k0s] = a0 | (b0 << 16);
            }
            #pragma unroll
            for (int ci = 0; ci < 8; ci++) {
                int c = ci + 8;
                uint a0 = (l1[ci>>1] >> ((ci&1)*16)) & 0xffffu;
                uint b0 = (h1[ci>>1] >> ((ci&1)*16)) & 0xffffu;
                int k0s = sk0 ^ ((c & 3) << 3);
                *(uint*)&sm_t[sp*648 + c*40 + k0s] = a0 | (b0 << 16);
            }
        }
        __syncthreads();

        {
            const ushort* mb = sm_ms + c15*40 + gx;
            const ushort* tb = sm_t  + c15*40 + gx;
            #pragma unroll
            for (int j = 0; j < 4; j++) {
                int cg = w + 4*j;
                int h  = cg >> 1;
                bf16x8 af  = *(const bf16x8*)&mb[h*640];
                bf16x8 bfr = *(const bf16x8*)&tb[cg*648];
                acc[j] = __builtin_amdgcn_mfma_f32_16x16x32_bf16(af, bfr, acc[j], 0, 0, 0);
            }
        }
    }

    __syncthreads();
    float* Ep = (float*)smem;
    #pragma unroll
    for (int j = 0; j < 4; j++) {
        int cg = w + 4*j;
        #pragma unroll
        for (int i = 0; i < 4; i++)
            Ep[cg*256 + (g*4 + i)*16 + c15] = acc[j][i];
    }
    __syncthreads();
    {
        int p = tid >> 4, r = tid & 15;
        float* dst = Pp + (((size_t)(ks*B_ + b)*16 + p)*N_ + (n0 + r)) * 16;
        const float* src = &Ep[p*256 + r*16];
        *(float4*)&dst[0]  = *(const float4*)&src[0];
        *(float4*)&dst[4]  = *(const float4*)&src[4];
        *(float4*)&dst[8]  = *(const float4*)&src[8];
        *(float4*)&dst[12] = *(const float4*)&src[12];
    }
}

// ---------------- reduce KS_ slabs -> bf16 panels; FINAL=1 adds inv-degree scale ----------------
template<int FINAL>
__global__ void chain_reduce(const float* __restrict__ Pp, ushort* __restrict__ outp,
                             const float* __restrict__ invd)
{
    int pidx = blockIdx.x * 256 + threadIdx.x;
    float4 s = make_float4(0.f, 0.f, 0.f, 0.f);
    #pragma unroll
    for (int ks = 0; ks < KS_; ks++) {
        float4 v = ((const float4*)Pp)[(size_t)ks*SLABF4_ + pidx];
        s.x += v.x; s.y += v.y; s.z += v.z; s.w += v.w;
    }
    if constexpr (FINAL) {
        int lin = pidx * 4;
        int n  = (lin >> 4) & (N_-1);
        int b  = lin >> 18;
        float sc = invd[b*N_ + n];
        s.x *= sc; s.y *= sc; s.z *= sc; s.w *= sc;
    }
    uint2 wv;
    wv.x = pack2_bf(s.x, s.y);
    wv.y = pack2_bf(s.z, s.w);
    ((uint2*)outp)[pidx] = wv;
}

// ---------------- V projection (SIMT, writes bf16 panels) ----------------
#define BK 16
__global__ void gemm_v(const float* __restrict__ A, const float* __restrict__ Bm,
                       const float* __restrict__ bias, ushort* __restrict__ C)
{
    __shared__ __align__(16) float As[BK][68];
    __shared__ __align__(16) float Bs[BK][68];
    int m0 = blockIdx.x * 64;
    int n0 = blockIdx.y * 64;
    int tid = threadIdx.x;
    int tx = tid & 15, ty = tid >> 4;

    float acc[4][4];
    #pragma unroll
    for (int i = 0; i < 4; i++)
        #pragma unroll
        for (int j = 0; j < 4; j++) acc[i][j] = 0.0f;

    for (int k0 = 0; k0 < D_; k0 += BK) {
        {
            int m = tid >> 2;
            int k = (tid & 3) * 4;
            float4 v = *(const float4*)&A[(size_t)(m0+m)*D_ + k0 + k];
            As[k+0][m] = v.x; As[k+1][m] = v.y; As[k+2][m] = v.z; As[k+3][m] = v.w;
        }
        {
            int k = tid >> 4;
            int n = (tid & 15) * 4;
            int c = n0 + n; int h = c >> 5; int ee = c & 31;
            float4 v = *(const float4*)&Bm[(size_t)h*D_*DH_ + (size_t)(k0+k)*DH_ + ee];
            *(float4*)&Bs[k][n] = v;
        }
        __syncthreads();
        #pragma unroll
        for (int k = 0; k < BK; k++) {
            float4 a4 = *(const float4*)&As[k][ty*4];
            float4 b4 = *(const float4*)&Bs[k][tx*4];
            acc[0][0] += a4.x*b4.x; acc[0][1] += a4.x*b4.y; acc[0][2] += a4.x*b4.z; acc[0][3] += a4.x*b4.w;
            acc[1][0] += a4.y*b4.x; acc[1][1] += a4.y*b4.y; acc[1][2] += a4.y*b4.z; acc[1][3] += a4.y*b4.w;
            acc[2][0] += a4.z*b4.x; acc[2][1] += a4.z*b4.y; acc[2][2] += a4.z*b4.z; acc[2][3] += a4.z*b4.w;
            acc[3][0] += a4.w*b4.x; acc[3][1] += a4.w*b4.y; acc[3][2] += a4.w*b4.z; acc[3][3] += a4.w*b4.w;
        }
        __syncthreads();
    }

    #pragma unroll
    for (int i = 0; i < 4; i++) {
        int row  = m0 + ty*4 + i;
        int nloc = n0 + tx*4;
        float o[4];
        #pragma unroll
        for (int j = 0; j < 4; j++) {
            int c = nloc + j;
            int h = c >> 5, ee = c & 31, n = row & (N_-1);
            o[j] = acc[i][j] + bias[(size_t)h*N_*DH_ + (size_t)n*DH_ + ee];
        }
        int bb = row >> 10, n = row & (N_-1);
        int cg = nloc >> 4, cc = nloc & 15;
        uint2 wv;
        wv.x = pack2_bf(o[0], o[1]);
        wv.y = pack2_bf(o[2], o[3]);
        *(uint2*)&C[(((size_t)bb*16 + cg)*N_ + n)*16 + cc] = wv;
    }
}

// ================= fused MFMA FFN kernels: BM=16, full-N blocks, grid 128 =================

// ---- gemm_r: resid = attn(panels)@W0 + x ; h = LN(resid, gamma,beta) -> bf16 ----
__global__ __launch_bounds__(256, 2)
void gemm_r(const ushort* __restrict__ attnp, const float* __restrict__ W0,
            const float* __restrict__ x, const float* __restrict__ gamma,
            const float* __restrict__ beta, float* __restrict__ resid,
            ushort* __restrict__ hbuf)
{
    __shared__ __align__(16) ushort As[16*40];
    __shared__ __align__(16) ushort Bs[256*40];
    __shared__ float lnb[16*257];
    __shared__ float2 stat[16];

    int m0 = blockIdx.x * 16;
    int b16 = (m0 >> 10) * 16;
    int nb  = m0 & (N_-1);
    int tid = threadIdx.x;
    int lane = tid & 63;
    int w = tid >> 6;
    int g = lane >> 4, c15 = lane & 15;
    int gx = (g ^ (c15 & 3)) * 8;

    int am = tid >> 4, ak2 = (tid & 15) * 2;
    int apos = am*40 + ((((ak2>>3) ^ (am&3))) << 3) + (ak2 & 7);
    int bn8 = (tid & 31) * 8;
    int bkq = (tid >> 5) * 4;
    int bpos0 = (((bkq>>3)) << 3) + (bkq & 7);

    f32x4 acc[4];
    #pragma unroll
    for (int j = 0; j < 4; j++) acc[j] = (f32x4){0.f,0.f,0.f,0.f};

    for (int ks = 0; ks < 8; ks++) {
        int k0 = ks * 32;
        int k = k0 + ak2;
        uint av = *(const uint*)&attnp[(((size_t)(b16 + (k>>4)))*N_ + nb + am)*16 + (k & 15)];
        float4 lo[4], hi[4];
        #pragma unroll
        for (int i = 0; i < 4; i++) {
            lo[i] = *(const float4*)&W0[(size_t)(k0+bkq+i)*D_ + bn8];
            hi[i] = *(const float4*)&W0[(size_t)(k0+bkq+i)*D_ + bn8 + 4];
        }
        if (ks) __syncthreads();
        *(uint*)&As[apos] = av;
        #pragma unroll
        for (int jn = 0; jn < 8; jn++) {
            int n = bn8 + jn;
            float v0 = (jn<4)? ((const float*)&lo[0])[jn] : ((const float*)&hi[0])[jn-4];
            float v1 = (jn<4)? ((const float*)&lo[1])[jn] : ((const float*)&hi[1])[jn-4];
            float v2 = (jn<4)? ((const float*)&lo[2])[jn] : ((const float*)&hi[2])[jn-4];
            float v3 = (jn<4)? ((const float*)&lo[3])[jn] : ((const float*)&hi[3])[jn-4];
            uint2 wv; wv.x = pack2_bf(v0, v1); wv.y = pack2_bf(v2, v3);
            *(uint2*)&Bs[n*40 + (bpos0 ^ ((n&3)<<3))] = wv;
        }
        __syncthreads();
        const ushort* ab = As + c15*40 + gx;
        #pragma unroll
        for (int nt = 0; nt < 4; nt++) {
            int n = w*64 + nt*16 + c15;
            bf16x8 af  = *(const bf16x8*)ab;
            bf16x8 bfr = *(const bf16x8*)&Bs[n*40 + gx];
            acc[nt] = __builtin_amdgcn_mfma_f32_16x16x32_bf16(af, bfr, acc[nt], 0, 0, 0);
        }
    }
    __syncthreads();

    // resid tile into LDS: resid = acc + x
    #pragma unroll
    for (int nt = 0; nt < 4; nt++) {
        int c = w*64 + nt*16 + c15;
        #pragma unroll
        for (int i = 0; i < 4; i++) {
            int r = g*4 + i;
            lnb[r*257 + c] = acc[nt][i] + x[(size_t)(m0+r)*D_ + c];
        }
    }
    __syncthreads();

    // row stats via 16-lane shfl groups
    {
        int rr = tid >> 4, sl = tid & 15;
        float sum = 0.f, sq = 0.f;
        #pragma unroll
        for (int j = 0; j < 16; j++) {
            float v = lnb[rr*257 + sl + 16*j];
            sum += v; sq += v*v;
        }
        #pragma unroll
        for (int m = 1; m < 16; m <<= 1) { sum += __shfl_xor(sum, m); sq += __shfl_xor(sq, m); }
        if (sl == 0) {
            float mean = sum * (1.0f/D_);
            float var  = fmaxf(sq * (1.0f/D_) - mean*mean, 0.f);
            stat[rr] = make_float2(mean, rsqrtf(var + 1e-12f));
        }
    }
    __syncthreads();

    // dense pass: write resid fp32 + h bf16
    {
        int rr = tid & 15, s2 = tid >> 4;
        float2 ms = stat[rr];
        int c0 = s2 * 16;
        uint hw[8];
        #pragma unroll
        for (int q = 0; q < 4; q++) {
            int c = c0 + q*4;
            float4 v = *(const float4*)&lnb[rr*257 + c];
            *(float4*)&resid[(size_t)(m0+rr)*D_ + c] = v;
            float4 gm = *(const float4*)&gamma[c];
            float4 bt = *(const float4*)&beta[c];
            float h0 = (v.x - ms.x)*ms.y*gm.x + bt.x;
            float h1 = (v.y - ms.x)*ms.y*gm.y + bt.y;
            float h2 = (v.z - ms.x)*ms.y*gm.z + bt.z;
            float h3 = (v.w - ms.x)*ms.y*gm.w + bt.w;
            hw[2*q]   = pack2_bf(h0, h1);
            hw[2*q+1] = pack2_bf(h2, h3);
        }
        ushort* hp = &hbuf[(size_t)(m0+rr)*D_ + c0];
        *(uint4*)&hp[0] = make_uint4(hw[0], hw[1], hw[2], hw[3]);
        *(uint4*)&hp[8] = make_uint4(hw[4], hw[5], hw[6], hw[7]);
    }
}

// ---- gemm_f1: f = LN(gelu(h@W1 + b1), gf, bf) -> bf16 ----
__global__ __launch_bounds__(256, 2)
void gemm_f1(const ushort* __restrict__ hbuf, const float* __restrict__ W1,
             const float* __restrict__ b1, const float* __restrict__ gf,
             const float* __restrict__ bfv, ushort* __restrict__ fout)
{
    __shared__ __align__(16) ushort As[16*40];
    __shared__ __align__(16) ushort Bs[512*40];
    __shared__ float lnb[16*513];
    __shared__ float2 stat[16];

    int m0 = blockIdx.x * 16;
    int tid = threadIdx.x;
    int lane = tid & 63;
    int w = tid >> 6;
    int g = lane >> 4, c15 = lane & 15;
    int gx = (g ^ (c15 & 3)) * 8;

    int am = tid >> 4, ak2 = (tid & 15) * 2;
    int apos = am*40 + ((((ak2>>3) ^ (am&3))) << 3) + (ak2 & 7);
    int bn8 = (tid & 63) * 8;
    int bk8 = (tid >> 6) * 8;

    f32x4 acc[8];
    #pragma unroll
    for (int j = 0; j < 8; j++) acc[j] = (f32x4){0.f,0.f,0.f,0.f};

    for (int ks = 0; ks < 8; ks++) {
        int k0 = ks * 32;
        uint av = *(const uint*)&hbuf[(size_t)(m0+am)*D_ + k0 + ak2];
        float4 q[16];
        #pragma unroll
        for (int i = 0; i < 8; i++) {
            q[2*i]   = *(const float4*)&W1[(size_t)(k0+bk8+i)*(2*D_) + bn8];
            q[2*i+1] = *(const float4*)&W1[(size_t)(k0+bk8+i)*(2*D_) + bn8 + 4];
        }
        if (ks) __syncthreads();
        *(uint*)&As[apos] = av;
        #pragma unroll
        for (int jn = 0; jn < 8; jn++) {
            int n = bn8 + jn;
            float e0 = (jn<4)? ((const float*)&q[0])[jn]  : ((const float*)&q[1])[jn-4];
            float e1 = (jn<4)? ((const float*)&q[2])[jn]  : ((const float*)&q[3])[jn-4];
            float e2 = (jn<4)? ((const float*)&q[4])[jn]  : ((const float*)&q[5])[jn-4];
            float e3 = (jn<4)? ((const float*)&q[6])[jn]  : ((const float*)&q[7])[jn-4];
            float e4 = (jn<4)? ((const float*)&q[8])[jn]  : ((const float*)&q[9])[jn-4];
            float e5 = (jn<4)? ((const float*)&q[10])[jn] : ((const float*)&q[11])[jn-4];
            float e6 = (jn<4)? ((const float*)&q[12])[jn] : ((const float*)&q[13])[jn-4];
            float e7 = (jn<4)? ((const float*)&q[14])[jn] : ((const float*)&q[15])[jn-4];
            uint4 wv;
            wv.x = pack2_bf(e0, e1); wv.y = pack2_bf(e2, e3);
            wv.z = pack2_bf(e4, e5); wv.w = pack2_bf(e6, e7);
            *(uint4*)&Bs[n*40 + ((((bk8>>3) ^ (n&3))) << 3)] = wv;
        }
        __syncthreads();
        const ushort* ab = As + c15*40 + gx;
        #pragma unroll
        for (int nt = 0; nt < 8; nt++) {
            int n = w*128 + nt*16 + c15;
            bf16x8 af  = *(const bf16x8*)ab;
            bf16x8 bfr = *(const bf16x8*)&Bs[n*40 + gx];
            acc[nt] = __builtin_amdgcn_mfma_f32_16x16x32_bf16(af, bfr, acc[nt], 0, 0, 0);
        }
    }
    __syncthreads();

    #pragma unroll
    for (int nt = 0; nt < 8; nt++) {
        int c = w*128 + nt*16 + c15;
        float bias = b1[c];
        #pragma unroll
        for (int i = 0; i < 4; i++) {
            int r = g*4 + i;
            float v = acc[nt][i] + bias;
            v = 0.5f * v * (1.0f + erff(v * 0.70710678118654752f));
            lnb[r*513 + c] = v;
        }
    }
    __syncthreads();

    {
        int rr = tid >> 4, sl = tid & 15;
        float sum = 0.f, sq = 0.f;
        #pragma unroll
        for (int j = 0; j < 32; j++) {
            float v = lnb[rr*513 + sl + 16*j];
            sum += v; sq += v*v;
        }
        #pragma unroll
        for (int m = 1; m < 16; m <<= 1) { sum += __shfl_xor(sum, m); sq += __shfl_xor(sq, m); }
        if (sl == 0) {
            float mean = sum * (1.0f/(2*D_));
            float var  = fmaxf(sq * (1.0f/(2*D_)) - mean*mean, 0.f);
            stat[rr] = make_float2(mean, rsqrtf(var + 1e-12f));
        }
    }
    __syncthreads();

    {
        int rr = tid & 15, s2 = tid >> 4;
        float2 ms = stat[rr];
        int c0 = s2 * 32;
        #pragma unroll
        for (int q = 0; q < 8; q++) {
            int c = c0 + q*4;
            float4 v = *(const float4*)&lnb[rr*513 + c];
            float4 gm = *(const float4*)&gf[c];
            float4 bt = *(const float4*)&bfv[c];
            float h0 = (v.x - ms.x)*ms.y*gm.x + bt.x;
            float h1 = (v.y - ms.x)*ms.y*gm.y + bt.y;
            float h2 = (v.z - ms.x)*ms.y*gm.z + bt.z;
            float h3 = (v.w - ms.x)*ms.y*gm.w + bt.w;
            *(uint2*)&fout[(size_t)(m0+rr)*(2*D_) + c] = make_uint2(pack2_bf(h0,h1), pack2_bf(h2,h3));
        }
    }
}

// ---- gemm_f2: out = f@W2 + b2f + resid ----
__global__ __launch_bounds__(256, 2)
void gemm_f2(const ushort* __restrict__ fbuf, const float* __restrict__ W2,
             const float* __restrict__ b2f, const float* __restrict__ resid,
             float* __restrict__ outp)
{
    __shared__ __align__(16) ushort As[16*40];
    __shared__ __align__(16) ushort Bs[256*40];
    __shared__ float lnb[16*257];

    int m0 = blockIdx.x * 16;
    int tid = threadIdx.x;
    int lane = tid & 63;
    int w = tid >> 6;
    int g = lane >> 4, c15 = lane & 15;
    int gx = (g ^ (c15 & 3)) * 8;

    int am = tid >> 4, ak2 = (tid & 15) * 2;
    int apos = am*40 + ((((ak2>>3) ^ (am&3))) << 3) + (ak2 & 7);
    int bn8 = (tid & 31) * 8;
    int bkq = (tid >> 5) * 4;
    int bpos0 = (((bkq>>3)) << 3) + (bkq & 7);

    f32x4 acc[4];
    #pragma unroll
    for (int j = 0; j < 4; j++) acc[j] = (f32x4){0.f,0.f,0.f,0.f};

    for (int ks = 0; ks < 16; ks++) {
        int k0 = ks * 32;
        uint av = *(const uint*)&fbuf[(size_t)(m0+am)*(2*D_) + k0 + ak2];
        float4 lo[4], hi[4];
        #pragma unroll
        for (int i = 0; i < 4; i++) {
            lo[i] = *(const float4*)&W2[(size_t)(k0+bkq+i)*D_ + bn8];
            hi[i] = *(const float4*)&W2[(size_t)(k0+bkq+i)*D_ + bn8 + 4];
        }
        if (ks) __syncthreads();
        *(uint*)&As[apos] = av;
        #pragma unroll
        for (int jn = 0; jn < 8; jn++) {
            int n = bn8 + jn;
            float v0 = (jn<4)? ((const float*)&lo[0])[jn] : ((const float*)&hi[0])[jn-4];
            float v1 = (jn<4)? ((const float*)&lo[1])[jn] : ((const float*)&hi[1])[jn-4];
            float v2 = (jn<4)? ((const float*)&lo[2])[jn] : ((const float*)&hi[2])[jn-4];
            float v3 = (jn<4)? ((const float*)&lo[3])[jn] : ((const float*)&hi[3])[jn-4];
            uint2 wv; wv.x = pack2_bf(v0, v1); wv.y = pack2_bf(v2, v3);
            *(uint2*)&Bs[n*40 + (bpos0 ^ ((n&3)<<3))] = wv;
        }
        __syncthreads();
        const ushort* ab = As + c15*40 + gx;
        #pragma unroll
        for (int nt = 0; nt < 4; nt++) {
            int n = w*64 + nt*16 + c15;
            bf16x8 af  = *(const bf16x8*)ab;
            bf16x8 bfr = *(const bf16x8*)&Bs[n*40 + gx];
            acc[nt] = __builtin_amdgcn_mfma_f32_16x16x32_bf16(af, bfr, acc[nt], 0, 0, 0);
        }
    }
    __syncthreads();

    #pragma unroll
    for (int nt = 0; nt < 4; nt++) {
        int c = w*64 + nt*16 + c15;
        #pragma unroll
        for (int i = 0; i < 4; i++)
            lnb[(g*4+i)*257 + c] = acc[nt][i];
    }
    __syncthreads();

    {
        int rr = tid & 15, s2 = tid >> 4;
        int c0 = s2 * 16;
        #pragma unroll
        for (int q = 0; q < 4; q++) {
            int c = c0 + q*4;
            float4 v  = *(const float4*)&lnb[rr*257 + c];
            float4 bb = *(const float4*)&b2f[c];
            float4 rs = *(const float4*)&resid[(size_t)(m0+rr)*D_ + c];
            float4 o = make_float4(v.x+bb.x+rs.x, v.y+bb.y+rs.y, v.z+bb.z+rs.z, v.w+bb.w+rs.w);
            *(float4*)&outp[(size_t)(m0+rr)*D_ + c] = o;
        }
    }
}

extern "C" void kernel_launch(void* const* d_in, const int* in_sizes, int n_in,
                              void* d_out, int out_size, void* d_ws, size_t ws_size,
                              hipStream_t stream)
{
    const float* adj    = (const float*)d_in[0];
    const float* degree = (const float*)d_in[1];
    const float* x      = (const float*)d_in[2];
    const float* kern   = (const float*)d_in[3];
    const float* Wv     = (const float*)d_in[4];
    const float* Bv     = (const float*)d_in[5];
    const float* W0     = (const float*)d_in[6];
    const float* gamma2 = (const float*)d_in[7];
    const float* beta2  = (const float*)d_in[8];
    const float* W1     = (const float*)d_in[9];
    const float* b1     = (const float*)d_in[10];
    const float* gf     = (const float*)d_in[11];
    const float* bf_    = (const float*)d_in[12];
    const float* W2     = (const float*)d_in[13];
    const float* b2f    = (const float*)d_in[14];
    float* out = (float*)d_out;
    float* ws  = (float*)d_ws;

    size_t off = 0;
    float* soft  = ws + off; off += 512;
    float* invd  = ws + off; off += 2048;
    float* T0    = ws + off; off += (size_t)ROWS_*D_;
    float* T1    = ws + off; off += (size_t)ROWS_*D_;
    float* resid = ws + off; off += (size_t)ROWS_*D_;
    float* hbuf  = ws + off; off += (size_t)ROWS_*D_;
    float* fbuf  = ws + off; off += (size_t)ROWS_*2*D_;
    float* fbuf2 = ws + off; off += (size_t)ROWS_*2*D_;
    float* Pp    = ws + off; off += (size_t)KS_*ROWS_*D_;
    ushort* adjp = (ushort*)(ws + off);
    (void)fbuf2;

    ushort* T0b = (ushort*)T0;
    ushort* T1b = (ushort*)T1;
    ushort* hb  = (ushort*)hbuf;
    ushort* fb  = (ushort*)fbuf;

    prep_kernel<<<9, 256, 0, stream>>>(kern, degree, soft, invd);
    adj_pack_kernel<<<(int)(ADJ_ELEMS_/8/256), 256, 0, stream>>>(adj, adjp);
    gemm_v<<<dim3(ROWS_/64, D_/64), 256, 0, stream>>>(x, Wv, Bv, T0b);

    int chain_grid  = B_*64*KS_;    // 1024
    int reduce_grid = SLABF4_/256;  // 512
    chain_mfma<<<chain_grid, 256, 0, stream>>>(adjp, soft, T0b, Pp, 3);
    chain_reduce<0><<<reduce_grid, 256, 0, stream>>>(Pp, T1b, invd);
    chain_mfma<<<chain_grid, 256, 0, stream>>>(adjp, soft, T1b, Pp, 2);
    chain_reduce<0><<<reduce_grid, 256, 0, stream>>>(Pp, T0b, invd);
    chain_mfma<<<chain_grid, 256, 0, stream>>>(adjp, soft, T0b, Pp, 1);
    chain_reduce<0><<<reduce_grid, 256, 0, stream>>>(Pp, T1b, invd);
    chain_mfma<<<chain_grid, 256, 0, stream>>>(adjp, soft, T1b, Pp, 0);
    chain_reduce<1><<<reduce_grid, 256, 0, stream>>>(Pp, T0b, invd);   // attn bf16 panels

    gemm_r <<<ROWS_/16, 256, 0, stream>>>(T0b, W0, x, gamma2, beta2, resid, hb);
    gemm_f1<<<ROWS_/16, 256, 0, stream>>>(hb, W1, b1, gf, bf_, fb);
    gemm_f2<<<ROWS_/16, 256, 0, stream>>>(fb, W2, b2f, resid, out);
}

// Round 9
// 195.125 us; speedup vs baseline: 3.2732x; 1.0278x over previous
//
#include <hip/hip_runtime.h>
#include <hip/hip_bf16.h>
#include <math.h>

#define B_ 2
#define A_ 9
#define N_ 1024
#define P_ 4
#define D_ 256
#define H_ 8
#define DH_ 32
#define ROWS_ (B_*N_)   // 2048
#define KS_ 8           // K-split factor for chain (k-slice 128)
#define ADJ_ELEMS_ ((size_t)B_*A_*N_*N_)
#define SLABF_ 524288   // Pp slab stride in floats (2*16*1024*16)
#define SLABF4_ (SLABF_/4)

typedef __attribute__((ext_vector_type(8))) short bf16x8;
typedef __attribute__((ext_vector_type(4))) float f32x4;

__device__ __forceinline__ uint pack2_bf(float x, float y) {
    uint ux = __float_as_uint(x); ux += 0x7fffu + ((ux >> 16) & 1u);
    uint uy = __float_as_uint(y); uy += 0x7fffu + ((uy >> 16) & 1u);
    return (ux >> 16) | (uy & 0xffff0000u);
}
__device__ __forceinline__ ushort bf1(float v) {
    uint u = __float_as_uint(v); u += 0x7fffu + ((u >> 16) & 1u);
    return (ushort)(u >> 16);
}
__device__ __forceinline__ float bflo(uint u){ return __uint_as_float(u << 16); }
__device__ __forceinline__ float bfhi(uint u){ return __uint_as_float(u & 0xffff0000u); }
__device__ __forceinline__ float bfs(ushort u){ return __uint_as_float((uint)u << 16); }

// ---------------- prep ----------------
__global__ void prep_kernel(const float* __restrict__ kernels, const float* __restrict__ degree,
                            float* __restrict__ soft, float* __restrict__ invd)
{
    int t = threadIdx.x;
    if (blockIdx.x == 0) {
        if (t < H_*P_) {
            int h = t >> 2, p = t & 3;
            float vals[A_];
            float m = 0.0f;
            #pragma unroll
            for (int a = 0; a < A_; a++) {
                float v = kernels[h*A_*P_ + a*P_ + p];
                v = v > 0.0f ? v : 0.0f;
                vals[a] = v;
                m = fmaxf(m, v);
            }
            float s = 0.0f;
            #pragma unroll
            for (int a = 0; a < A_; a++) { vals[a] = expf(vals[a] - m); s += vals[a]; }
            float inv = 1.0f / s;
            #pragma unroll
            for (int a = 0; a < A_; a++) soft[h*A_*P_ + a*P_ + p] = vals[a] * inv;
        }
    } else {
        int idx = (blockIdx.x - 1) * 256 + t;
        if (idx < ROWS_) {
            int b = idx >> 10, n = idx & (N_-1);
            invd[idx] = 1.0f / degree[(size_t)b*N_*N_ + (size_t)n*N_ + n];
        }
    }
}

// ---------------- MFMA chain step. PACK=1: read fp32 adjacency + write bf16 adjp slab ----------------
template<int PACK>
__global__ __launch_bounds__(256, 4)
void chain_mfma(const float* __restrict__ adjf, ushort* __restrict__ adjp,
                const float* __restrict__ soft,
                const ushort* __restrict__ Tin, float* __restrict__ Pp, int step)
{
    __shared__ __align__(16) ushort smem[8*640 + 16*648];
    __shared__ float soft_s[8][9];
    ushort* sm_ms = smem;
    ushort* sm_t  = smem + 8*640;

    int bid    = blockIdx.x;
    int ks     = bid & (KS_-1);
    int rowblk = (bid >> 3) & 63;
    int b      = bid >> 9;
    int n0     = rowblk * 16;
    int tid    = threadIdx.x;
    int lane   = tid & 63;
    int w      = tid >> 6;

    if (tid < 72) { int h = tid/9, a = tid%9; soft_s[h][a] = soft[h*A_*P_ + a*P_ + step]; }
    __syncthreads();

    int mr   = tid >> 4;
    int mk2  = (tid & 15) * 2;
    int mk2s = mk2 ^ ((mr & 3) << 3);
    ushort* ablk = adjp + (size_t)((b*64 + rowblk)*8 + ks) * 18432;

    int sp  = tid >> 4;
    int sk0 = (tid & 15) * 2;
    const ushort* tbase = Tin + ((size_t)(b*16 + sp)*1024 + (size_t)ks*128) * 16;

    int g   = lane >> 4;
    int c15 = lane & 15;
    int gx  = (g ^ (c15 & 3)) * 8;

    f32x4 acc[4];
    #pragma unroll
    for (int j = 0; j < 4; j++) acc[j] = (f32x4){0.f, 0.f, 0.f, 0.f};

    for (int chunk = 0; chunk < 4; chunk++) {
        float lo[9], hi[9];
        if constexpr (PACK) {
            #pragma unroll
            for (int a = 0; a < A_; a++) {
                float2 v = *(const float2*)&adjf[(((size_t)b*A_ + a)*N_ + (n0+mr))*N_
                                                 + ks*128 + chunk*32 + mk2];
                lo[a] = v.x; hi[a] = v.y;
            }
        } else {
            #pragma unroll
            for (int a = 0; a < A_; a++) {
                uint av = *(const uint*)&ablk[chunk*4608 + (a*16 + mr)*32 + mk2];
                lo[a] = bflo(av); hi[a] = bfhi(av);
            }
        }
        const ushort* tsl = tbase + (size_t)(chunk*32 + sk0) * 16;
        uint4 q0 = *(const uint4*)(tsl + 0);
        uint4 q1 = *(const uint4*)(tsl + 8);
        uint4 q2 = *(const uint4*)(tsl + 16);
        uint4 q3 = *(const uint4*)(tsl + 24);

        if constexpr (PACK) {
            // write raw bf16 adjacency slab for steps 2..0 (block-consumption order)
            #pragma unroll
            for (int a = 0; a < A_; a++)
                *(uint*)&ablk[chunk*4608 + (a*16 + mr)*32 + mk2] = pack2_bf(lo[a], hi[a]);
        }

        if (chunk) __syncthreads();

        // ---- mix all 8 heads into sm_ms ----
        #pragma unroll
        for (int h = 0; h < H_; h++) {
            float s0 = soft_s[h][0]*lo[0];
            float s1 = soft_s[h][0]*hi[0];
            #pragma unroll
            for (int a = 1; a < A_; a++) { s0 += soft_s[h][a]*lo[a]; s1 += soft_s[h][a]*hi[a]; }
            *(uint*)&sm_ms[h*640 + mr*40 + mk2s] = pack2_bf(s0, s1);
        }
        // ---- transpose-stage T chunk ----
        {
            uint l0[4] = {q0.x, q0.y, q0.z, q0.w};
            uint l1[4] = {q1.x, q1.y, q1.z, q1.w};
            uint h0[4] = {q2.x, q2.y, q2.z, q2.w};
            uint h1[4] = {q3.x, q3.y, q3.z, q3.w};
            #pragma unroll
            for (int ci = 0; ci < 8; ci++) {
                uint a0 = (l0[ci>>1] >> ((ci&1)*16)) & 0xffffu;
                uint b0 = (h0[ci>>1] >> ((ci&1)*16)) & 0xffffu;
                int k0s = sk0 ^ ((ci & 3) << 3);
                *(uint*)&sm_t[sp*648 + ci*40 + k0s] = a0 | (b0 << 16);
            }
            #pragma unroll
            for (int ci = 0; ci < 8; ci++) {
                int c = ci + 8;
                uint a0 = (l1[ci>>1] >> ((ci&1)*16)) & 0xffffu;
                uint b0 = (h1[ci>>1] >> ((ci&1)*16)) & 0xffffu;
                int k0s = sk0 ^ ((c & 3) << 3);
                *(uint*)&sm_t[sp*648 + c*40 + k0s] = a0 | (b0 << 16);
            }
        }
        __syncthreads();

        {
            const ushort* mb = sm_ms + c15*40 + gx;
            const ushort* tb = sm_t  + c15*40 + gx;
            #pragma unroll
            for (int j = 0; j < 4; j++) {
                int cg = w + 4*j;
                int h  = cg >> 1;
                bf16x8 af  = *(const bf16x8*)&mb[h*640];
                bf16x8 bfr = *(const bf16x8*)&tb[cg*648];
                acc[j] = __builtin_amdgcn_mfma_f32_16x16x32_bf16(af, bfr, acc[j], 0, 0, 0);
            }
        }
    }

    __syncthreads();
    float* Ep = (float*)smem;
    #pragma unroll
    for (int j = 0; j < 4; j++) {
        int cg = w + 4*j;
        #pragma unroll
        for (int i = 0; i < 4; i++)
            Ep[cg*256 + (g*4 + i)*16 + c15] = acc[j][i];
    }
    __syncthreads();
    {
        int p = tid >> 4, r = tid & 15;
        float* dst = Pp + (((size_t)(ks*B_ + b)*16 + p)*N_ + (n0 + r)) * 16;
        const float* src = &Ep[p*256 + r*16];
        *(float4*)&dst[0]  = *(const float4*)&src[0];
        *(float4*)&dst[4]  = *(const float4*)&src[4];
        *(float4*)&dst[8]  = *(const float4*)&src[8];
        *(float4*)&dst[12] = *(const float4*)&src[12];
    }
}

// ---------------- reduce KS_ slabs -> bf16 T panels ----------------
__global__ void chain_reduce(const float* __restrict__ Pp, ushort* __restrict__ outp)
{
    int pidx = blockIdx.x * 256 + threadIdx.x;
    float4 s = make_float4(0.f, 0.f, 0.f, 0.f);
    #pragma unroll
    for (int ks = 0; ks < KS_; ks++) {
        float4 v = ((const float4*)Pp)[(size_t)ks*SLABF4_ + pidx];
        s.x += v.x; s.y += v.y; s.z += v.z; s.w += v.w;
    }
    uint2 wv;
    wv.x = pack2_bf(s.x, s.y);
    wv.y = pack2_bf(s.z, s.w);
    ((uint2*)outp)[pidx] = wv;
}

// ---------------- V projection (SIMT, writes bf16 panels) ----------------
#define BK 16
__global__ void gemm_v(const float* __restrict__ A, const float* __restrict__ Bm,
                       const float* __restrict__ bias, ushort* __restrict__ C)
{
    __shared__ __align__(16) float As[BK][68];
    __shared__ __align__(16) float Bs[BK][68];
    int m0 = blockIdx.x * 64;
    int n0 = blockIdx.y * 64;
    int tid = threadIdx.x;
    int tx = tid & 15, ty = tid >> 4;

    float acc[4][4];
    #pragma unroll
    for (int i = 0; i < 4; i++)
        #pragma unroll
        for (int j = 0; j < 4; j++) acc[i][j] = 0.0f;

    for (int k0 = 0; k0 < D_; k0 += BK) {
        {
            int m = tid >> 2;
            int k = (tid & 3) * 4;
            float4 v = *(const float4*)&A[(size_t)(m0+m)*D_ + k0 + k];
            As[k+0][m] = v.x; As[k+1][m] = v.y; As[k+2][m] = v.z; As[k+3][m] = v.w;
        }
        {
            int k = tid >> 4;
            int n = (tid & 15) * 4;
            int c = n0 + n; int h = c >> 5; int ee = c & 31;
            float4 v = *(const float4*)&Bm[(size_t)h*D_*DH_ + (size_t)(k0+k)*DH_ + ee];
            *(float4*)&Bs[k][n] = v;
        }
        __syncthreads();
        #pragma unroll
        for (int k = 0; k < BK; k++) {
            float4 a4 = *(const float4*)&As[k][ty*4];
            float4 b4 = *(const float4*)&Bs[k][tx*4];
            acc[0][0] += a4.x*b4.x; acc[0][1] += a4.x*b4.y; acc[0][2] += a4.x*b4.z; acc[0][3] += a4.x*b4.w;
            acc[1][0] += a4.y*b4.x; acc[1][1] += a4.y*b4.y; acc[1][2] += a4.y*b4.z; acc[1][3] += a4.y*b4.w;
            acc[2][0] += a4.z*b4.x; acc[2][1] += a4.z*b4.y; acc[2][2] += a4.z*b4.z; acc[2][3] += a4.z*b4.w;
            acc[3][0] += a4.w*b4.x; acc[3][1] += a4.w*b4.y; acc[3][2] += a4.w*b4.z; acc[3][3] += a4.w*b4.w;
        }
        __syncthreads();
    }

    #pragma unroll
    for (int i = 0; i < 4; i++) {
        int row  = m0 + ty*4 + i;
        int nloc = n0 + tx*4;
        float o[4];
        #pragma unroll
        for (int j = 0; j < 4; j++) {
            int c = nloc + j;
            int h = c >> 5, ee = c & 31, n = row & (N_-1);
            o[j] = acc[i][j] + bias[(size_t)h*N_*DH_ + (size_t)n*DH_ + ee];
        }
        int bb = row >> 10, n = row & (N_-1);
        int cg = nloc >> 4, cc = nloc & 15;
        uint2 wv;
        wv.x = pack2_bf(o[0], o[1]);
        wv.y = pack2_bf(o[2], o[3]);
        *(uint2*)&C[(((size_t)bb*16 + cg)*N_ + n)*16 + cc] = wv;
    }
}

// ================= fully fused FFN tail (1 kernel, 512 threads, grid 128) =================
// Phase R: attn(=sum Pp slabs * invd) @ W0 + x -> resid (LDS fp32) -> LN -> h (LDS bf16)
// Phase F1: h @ W1 + b1 -> gelu -> f (LDS bf16) -> LN in place
// Phase F2: f @ W2 + b2f + resid -> out (global fp32)
__global__ __launch_bounds__(512, 1)
void ffn_fused(const float* __restrict__ Pp, const float* __restrict__ invd,
               const float* __restrict__ W0, const float* __restrict__ x,
               const float* __restrict__ gamma, const float* __restrict__ beta,
               const float* __restrict__ W1, const float* __restrict__ b1,
               const float* __restrict__ gf, const float* __restrict__ bfv,
               const float* __restrict__ W2, const float* __restrict__ b2f,
               float* __restrict__ outp)
{
    __shared__ __align__(16) ushort arena[41760];   // 83.5 KB
    ushort* As  = arena;                 // 16*40
    ushort* Bs  = arena + 640;           // 512*40
    ushort* hL  = arena + 21120;         // 16*256
    ushort* fL  = arena + 25216;         // 16*512
    float*  lnb = (float*)(arena + 33408);   // 16*257 fp32 (resid, persists)
    float2* statR = (float2*)(arena + 41632);
    float2* statF = statR + 16;

    int m0  = blockIdx.x * 16;
    int b   = m0 >> 10;
    int nb  = m0 & (N_-1);
    int tid = threadIdx.x;
    int lane = tid & 63;
    int w = tid >> 6;                 // 0..7
    int g = lane >> 4, c15 = lane & 15;
    int gx = (g ^ (c15 & 3)) * 8;

    // A-stage ids (tid<256)
    int am  = tid >> 4;               // 0..15 row
    int ak2 = (tid & 15) * 2;         // k-pair
    int apos = am*40 + ((((ak2>>3) ^ (am&3))) << 3) + (ak2 & 7);
    float idv = 0.f;
    if (tid < 256) idv = invd[b*N_ + nb + am];

    // ---------------- Phase R ----------------
    f32x4 accR[2];
    accR[0] = (f32x4){0.f,0.f,0.f,0.f};
    accR[1] = (f32x4){0.f,0.f,0.f,0.f};
    {
        int n8  = (tid & 31) * 8;
        int kq2 = (tid >> 5) * 2;
        int bposR = ((kq2 >> 3) << 3) + (kq2 & 7);
        for (int ksi = 0; ksi < 8; ksi++) {
            int k0 = ksi * 32;
            uint av = 0;
            if (tid < 256) {
                int k = k0 + ak2;
                size_t base = (((size_t)(b*16 + (k>>4)))*N_ + nb + am)*16 + (k & 15);
                float s0 = 0.f, s1 = 0.f;
                #pragma unroll
                for (int sl = 0; sl < 8; sl++) {
                    float2 v = *(const float2*)&Pp[(size_t)sl*SLABF_ + base];
                    s0 += v.x; s1 += v.y;
                }
                av = pack2_bf(s0*idv, s1*idv);
            }
            float4 r0a = *(const float4*)&W0[(size_t)(k0+kq2  )*D_ + n8];
            float4 r0b = *(const float4*)&W0[(size_t)(k0+kq2  )*D_ + n8 + 4];
            float4 r1a = *(const float4*)&W0[(size_t)(k0+kq2+1)*D_ + n8];
            float4 r1b = *(const float4*)&W0[(size_t)(k0+kq2+1)*D_ + n8 + 4];
            if (ksi) __syncthreads();
            if (tid < 256) *(uint*)&As[apos] = av;
            #pragma unroll
            for (int jn = 0; jn < 8; jn++) {
                int n = n8 + jn;
                float v0 = (jn<4)? ((const float*)&r0a)[jn] : ((const float*)&r0b)[jn-4];
                float v1 = (jn<4)? ((const float*)&r1a)[jn] : ((const float*)&r1b)[jn-4];
                *(uint*)&Bs[n*40 + (bposR ^ ((n&3)<<3))] = pack2_bf(v0, v1);
            }
            __syncthreads();
            const ushort* ab = As + c15*40 + gx;
            #pragma unroll
            for (int nt = 0; nt < 2; nt++) {
                int n = (w*2 + nt)*16 + c15;
                bf16x8 af  = *(const bf16x8*)ab;
                bf16x8 bfr = *(const bf16x8*)&Bs[n*40 + gx];
                accR[nt] = __builtin_amdgcn_mfma_f32_16x16x32_bf16(af, bfr, accR[nt], 0, 0, 0);
            }
        }
    }
    __syncthreads();
    // resid = acc + x  -> lnb
    #pragma unroll
    for (int nt = 0; nt < 2; nt++) {
        int c = (w*2 + nt)*16 + c15;
        #pragma unroll
        for (int i = 0; i < 4; i++) {
            int r = g*4 + i;
            lnb[r*257 + c] = accR[nt][i] + x[(size_t)(m0+r)*D_ + c];
        }
    }
    __syncthreads();
    if (tid < 256) {
        int rr = tid >> 4, sl = tid & 15;
        float sum = 0.f, sq = 0.f;
        #pragma unroll
        for (int j = 0; j < 16; j++) {
            float v = lnb[rr*257 + sl + 16*j];
            sum += v; sq += v*v;
        }
        #pragma unroll
        for (int m = 1; m < 16; m <<= 1) { sum += __shfl_xor(sum, m); sq += __shfl_xor(sq, m); }
        if (sl == 0) {
            float mean = sum * (1.0f/D_);
            float var  = fmaxf(sq * (1.0f/D_) - mean*mean, 0.f);
            statR[rr] = make_float2(mean, rsqrtf(var + 1e-12f));
        }
    }
    __syncthreads();
    if (tid < 256) {
        int rr = tid & 15, s2 = tid >> 4;
        float2 ms = statR[rr];
        int c0 = s2 * 16;
        uint hw[8];
        #pragma unroll
        for (int q = 0; q < 4; q++) {
            int c = c0 + q*4;
            float4 v = *(const float4*)&lnb[rr*257 + c];
            float4 gm = *(const float4*)&gamma[c];
            float4 bt = *(const float4*)&beta[c];
            float h0 = (v.x - ms.x)*ms.y*gm.x + bt.x;
            float h1 = (v.y - ms.x)*ms.y*gm.y + bt.y;
            float h2 = (v.z - ms.x)*ms.y*gm.z + bt.z;
            float h3 = (v.w - ms.x)*ms.y*gm.w + bt.w;
            hw[2*q]   = pack2_bf(h0, h1);
            hw[2*q+1] = pack2_bf(h2, h3);
        }
        *(uint4*)&hL[rr*256 + c0    ] = make_uint4(hw[0], hw[1], hw[2], hw[3]);
        *(uint4*)&hL[rr*256 + c0 + 8] = make_uint4(hw[4], hw[5], hw[6], hw[7]);
    }
    __syncthreads();

    // ---------------- Phase F1 ----------------
    f32x4 acc1[4];
    #pragma unroll
    for (int j = 0; j < 4; j++) acc1[j] = (f32x4){0.f,0.f,0.f,0.f};
    {
        int n8  = (tid & 63) * 8;
        int kq4 = (tid >> 6) * 4;
        for (int ksi = 0; ksi < 8; ksi++) {
            int k0 = ksi * 32;
            uint av = 0;
            if (tid < 256) av = *(const uint*)&hL[am*256 + k0 + ak2];
            float4 q0a = *(const float4*)&W1[(size_t)(k0+kq4  )*(2*D_) + n8];
            float4 q0b = *(const float4*)&W1[(size_t)(k0+kq4  )*(2*D_) + n8 + 4];
            float4 q1a = *(const float4*)&W1[(size_t)(k0+kq4+1)*(2*D_) + n8];
            float4 q1b = *(const float4*)&W1[(size_t)(k0+kq4+1)*(2*D_) + n8 + 4];
            float4 q2a = *(const float4*)&W1[(size_t)(k0+kq4+2)*(2*D_) + n8];
            float4 q2b = *(const float4*)&W1[(size_t)(k0+kq4+2)*(2*D_) + n8 + 4];
            float4 q3a = *(const float4*)&W1[(size_t)(k0+kq4+3)*(2*D_) + n8];
            float4 q3b = *(const float4*)&W1[(size_t)(k0+kq4+3)*(2*D_) + n8 + 4];
            __syncthreads();
            if (tid < 256) *(uint*)&As[apos] = av;
            #pragma unroll
            for (int jn = 0; jn < 8; jn++) {
                int n = n8 + jn;
                float e0 = (jn<4)? ((const float*)&q0a)[jn] : ((const float*)&q0b)[jn-4];
                float e1 = (jn<4)? ((const float*)&q1a)[jn] : ((const float*)&q1b)[jn-4];
                float e2 = (jn<4)? ((const float*)&q2a)[jn] : ((const float*)&q2b)[jn-4];
                float e3 = (jn<4)? ((const float*)&q3a)[jn] : ((const float*)&q3b)[jn-4];
                int pos = ((((kq4>>3) ^ (n&3))) << 3) + (kq4 & 7);
                *(uint2*)&Bs[n*40 + pos] = make_uint2(pack2_bf(e0,e1), pack2_bf(e2,e3));
            }
            __syncthreads();
            const ushort* ab = As + c15*40 + gx;
            #pragma unroll
            for (int nt = 0; nt < 4; nt++) {
                int n = (w*4 + nt)*16 + c15;
                bf16x8 af  = *(const bf16x8*)ab;
                bf16x8 bfr = *(const bf16x8*)&Bs[n*40 + gx];
                acc1[nt] = __builtin_amdgcn_mfma_f32_16x16x32_bf16(af, bfr, acc1[nt], 0, 0, 0);
            }
        }
    }
    __syncthreads();
    // gelu -> fL bf16
    #pragma unroll
    for (int nt = 0; nt < 4; nt++) {
        int c = (w*4 + nt)*16 + c15;
        float bias = b1[c];
        #pragma unroll
        for (int i = 0; i < 4; i++) {
            int r = g*4 + i;
            float v = acc1[nt][i] + bias;
            v = 0.5f * v * (1.0f + erff(v * 0.70710678118654752f));
            fL[r*512 + c] = bf1(v);
        }
    }
    __syncthreads();
    if (tid < 256) {
        int rr = tid >> 4, sl = tid & 15;
        float sum = 0.f, sq = 0.f;
        #pragma unroll
        for (int j = 0; j < 32; j++) {
            float v = bfs(fL[rr*512 + sl + 16*j]);
            sum += v; sq += v*v;
        }
        #pragma unroll
        for (int m = 1; m < 16; m <<= 1) { sum += __shfl_xor(sum, m); sq += __shfl_xor(sq, m); }
        if (sl == 0) {
            float mean = sum * (1.0f/(2*D_));
            float var  = fmaxf(sq * (1.0f/(2*D_)) - mean*mean, 0.f);
            statF[rr] = make_float2(mean, rsqrtf(var + 1e-12f));
        }
    }
    __syncthreads();
    if (tid < 256) {
        int rr = tid & 15, s2 = tid >> 4;
        float2 ms = statF[rr];
        int c0 = s2 * 32;
        #pragma unroll
        for (int q = 0; q < 8; q++) {
            int c = c0 + q*4;
            uint2 u = *(const uint2*)&fL[rr*512 + c];
            float v0 = (bflo(u.x) - ms.x)*ms.y*gf[c+0] + bfv[c+0];
            float v1 = (bfhi(u.x) - ms.x)*ms.y*gf[c+1] + bfv[c+1];
            float v2 = (bflo(u.y) - ms.x)*ms.y*gf[c+2] + bfv[c+2];
            float v3 = (bfhi(u.y) - ms.x)*ms.y*gf[c+3] + bfv[c+3];
            *(uint2*)&fL[rr*512 + c] = make_uint2(pack2_bf(v0,v1), pack2_bf(v2,v3));
        }
    }
    __syncthreads();

    // ---------------- Phase F2 ----------------
    f32x4 acc2[2];
    acc2[0] = (f32x4){0.f,0.f,0.f,0.f};
    acc2[1] = (f32x4){0.f,0.f,0.f,0.f};
    {
        int n8  = (tid & 31) * 8;
        int kq2 = (tid >> 5) * 2;
        int bposR = ((kq2 >> 3) << 3) + (kq2 & 7);
        for (int ksi = 0; ksi < 16; ksi++) {
            int k0 = ksi * 32;
            uint av = 0;
            if (tid < 256) av = *(const uint*)&fL[am*512 + k0 + ak2];
            float4 r0a = *(const float4*)&W2[(size_t)(k0+kq2  )*D_ + n8];
            float4 r0b = *(const float4*)&W2[(size_t)(k0+kq2  )*D_ + n8 + 4];
            float4 r1a = *(const float4*)&W2[(size_t)(k0+kq2+1)*D_ + n8];
            float4 r1b = *(const float4*)&W2[(size_t)(k0+kq2+1)*D_ + n8 + 4];
            __syncthreads();
            if (tid < 256) *(uint*)&As[apos] = av;
            #pragma unroll
            for (int jn = 0; jn < 8; jn++) {
                int n = n8 + jn;
                float v0 = (jn<4)? ((const float*)&r0a)[jn] : ((const float*)&r0b)[jn-4];
                float v1 = (jn<4)? ((const float*)&r1a)[jn] : ((const float*)&r1b)[jn-4];
                *(uint*)&Bs[n*40 + (bposR ^ ((n&3)<<3))] = pack2_bf(v0, v1);
            }
            __syncthreads();
            const ushort* ab = As + c15*40 + gx;
            #pragma unroll
            for (int nt = 0; nt < 2; nt++) {
                int n = (w*2 + nt)*16 + c15;
                bf16x8 af  = *(const bf16x8*)ab;
                bf16x8 bfr = *(const bf16x8*)&Bs[n*40 + gx];
                acc2[nt] = __builtin_amdgcn_mfma_f32_16x16x32_bf16(af, bfr, acc2[nt], 0, 0, 0);
            }
        }
    }
    __syncthreads();
    {
        float* esc = (float*)(arena + 640);   // reuse Bs region (16x257 fp32)
        #pragma unroll
        for (int nt = 0; nt < 2; nt++) {
            int c = (w*2 + nt)*16 + c15;
            #pragma unroll
            for (int i = 0; i < 4; i++)
                esc[(g*4+i)*257 + c] = acc2[nt][i];
        }
        __syncthreads();
        if (tid < 256) {
            int rr = tid & 15, s2 = tid >> 4;
            int c0 = s2 * 16;
            #pragma unroll
            for (int q = 0; q < 4; q++) {
                int c = c0 + q*4;
                float4 v  = *(const float4*)&esc[rr*257 + c];
                float4 bb = *(const float4*)&b2f[c];
                float4 rs = *(const float4*)&lnb[rr*257 + c];
                float4 o = make_float4(v.x+bb.x+rs.x, v.y+bb.y+rs.y, v.z+bb.z+rs.z, v.w+bb.w+rs.w);
                *(float4*)&outp[(size_t)(m0+rr)*D_ + c] = o;
            }
        }
    }
}

extern "C" void kernel_launch(void* const* d_in, const int* in_sizes, int n_in,
                              void* d_out, int out_size, void* d_ws, size_t ws_size,
                              hipStream_t stream)
{
    const float* adj    = (const float*)d_in[0];
    const float* degree = (const float*)d_in[1];
    const float* x      = (const float*)d_in[2];
    const float* kern   = (const float*)d_in[3];
    const float* Wv     = (const float*)d_in[4];
    const float* Bv     = (const float*)d_in[5];
    const float* W0     = (const float*)d_in[6];
    const float* gamma2 = (const float*)d_in[7];
    const float* beta2  = (const float*)d_in[8];
    const float* W1     = (const float*)d_in[9];
    const float* b1     = (const float*)d_in[10];
    const float* gf     = (const float*)d_in[11];
    const float* bf_    = (const float*)d_in[12];
    const float* W2     = (const float*)d_in[13];
    const float* b2f    = (const float*)d_in[14];
    float* out = (float*)d_out;
    float* ws  = (float*)d_ws;

    size_t off = 0;
    float* soft  = ws + off; off += 512;
    float* invd  = ws + off; off += 2048;
    float* T0    = ws + off; off += (size_t)ROWS_*D_;
    float* T1    = ws + off; off += (size_t)ROWS_*D_;
    float* Pp    = ws + off; off += (size_t)KS_*ROWS_*D_;   // 16.8MB fp32 slabs
    ushort* adjp = (ushort*)(ws + off);                      // 37.75MB bf16

    ushort* T0b = (ushort*)T0;
    ushort* T1b = (ushort*)T1;

    prep_kernel<<<9, 256, 0, stream>>>(kern, degree, soft, invd);
    gemm_v<<<dim3(ROWS_/64, D_/64), 256, 0, stream>>>(x, Wv, Bv, T0b);

    int chain_grid  = B_*64*KS_;    // 1024
    int reduce_grid = SLABF4_/256;  // 512
    // step 3 reads fp32 adjacency and writes the bf16 packed slab for steps 2..0
    chain_mfma<1><<<chain_grid, 256, 0, stream>>>(adj, adjp, soft, T0b, Pp, 3);
    chain_reduce<<<reduce_grid, 256, 0, stream>>>(Pp, T1b);
    chain_mfma<0><<<chain_grid, 256, 0, stream>>>(adj, adjp, soft, T1b, Pp, 2);
    chain_reduce<<<reduce_grid, 256, 0, stream>>>(Pp, T0b);
    chain_mfma<0><<<chain_grid, 256, 0, stream>>>(adj, adjp, soft, T0b, Pp, 1);
    chain_reduce<<<reduce_grid, 256, 0, stream>>>(Pp, T1b);
    chain_mfma<0><<<chain_grid, 256, 0, stream>>>(adj, adjp, soft, T1b, Pp, 0);
    // fused tail: slab-sum + invd + W0/LN/W1/gelu/LN/W2 + residual -> out
    ffn_fused<<<ROWS_/16, 512, 0, stream>>>(Pp, invd, W0, x, gamma2, beta2,
                                            W1, b1, gf, bf_, W2, b2f, out);
}

// Round 10
// 182.644 us; speedup vs baseline: 3.4969x; 1.0683x over previous
//
#include <hip/hip_runtime.h>
#include <hip/hip_bf16.h>
#include <math.h>

#define B_ 2
#define A_ 9
#define N_ 1024
#define P_ 4
#define D_ 256
#define H_ 8
#define DH_ 32
#define ROWS_ (B_*N_)   // 2048
#define KS_ 8           // K-split factor for chain (k-slice 128)
#define ADJ_ELEMS_ ((size_t)B_*A_*N_*N_)
#define SLABF_ 524288   // Pp slab stride in floats (2*16*1024*16)
#define SLABF4_ (SLABF_/4)

typedef __attribute__((ext_vector_type(8))) short bf16x8;
typedef __attribute__((ext_vector_type(4))) float f32x4;

__device__ __forceinline__ uint pack2_bf(float x, float y) {
    uint ux = __float_as_uint(x); ux += 0x7fffu + ((ux >> 16) & 1u);
    uint uy = __float_as_uint(y); uy += 0x7fffu + ((uy >> 16) & 1u);
    return (ux >> 16) | (uy & 0xffff0000u);
}
__device__ __forceinline__ float bflo(uint u){ return __uint_as_float(u << 16); }
__device__ __forceinline__ float bfhi(uint u){ return __uint_as_float(u & 0xffff0000u); }

// ---------------- prep ----------------
__global__ void prep_kernel(const float* __restrict__ kernels, const float* __restrict__ degree,
                            float* __restrict__ soft, float* __restrict__ invd)
{
    int t = threadIdx.x;
    if (blockIdx.x == 0) {
        if (t < H_*P_) {
            int h = t >> 2, p = t & 3;
            float vals[A_];
            float m = 0.0f;
            #pragma unroll
            for (int a = 0; a < A_; a++) {
                float v = kernels[h*A_*P_ + a*P_ + p];
                v = v > 0.0f ? v : 0.0f;
                vals[a] = v;
                m = fmaxf(m, v);
            }
            float s = 0.0f;
            #pragma unroll
            for (int a = 0; a < A_; a++) { vals[a] = expf(vals[a] - m); s += vals[a]; }
            float inv = 1.0f / s;
            #pragma unroll
            for (int a = 0; a < A_; a++) soft[h*A_*P_ + a*P_ + p] = vals[a] * inv;
        }
    } else {
        int idx = (blockIdx.x - 1) * 256 + t;
        if (idx < ROWS_) {
            int b = idx >> 10, n = idx & (N_-1);
            invd[idx] = 1.0f / degree[(size_t)b*N_*N_ + (size_t)n*N_ + n];
        }
    }
}

// ---------------- MFMA chain step. PACK=1: read fp32 adjacency + write bf16 adjp slab ----------------
template<int PACK>
__global__ __launch_bounds__(256, 4)
void chain_mfma(const float* __restrict__ adjf, ushort* __restrict__ adjp,
                const float* __restrict__ soft,
                const ushort* __restrict__ Tin, float* __restrict__ Pp, int step)
{
    __shared__ __align__(16) ushort smem[8*640 + 16*648];
    __shared__ float soft_s[8][9];
    ushort* sm_ms = smem;
    ushort* sm_t  = smem + 8*640;

    int bid    = blockIdx.x;
    int ks     = bid & (KS_-1);
    int rowblk = (bid >> 3) & 63;
    int b      = bid >> 9;
    int n0     = rowblk * 16;
    int tid    = threadIdx.x;
    int lane   = tid & 63;
    int w      = tid >> 6;

    if (tid < 72) { int h = tid/9, a = tid%9; soft_s[h][a] = soft[h*A_*P_ + a*P_ + step]; }
    __syncthreads();

    int mr   = tid >> 4;
    int mk2  = (tid & 15) * 2;
    int mk2s = mk2 ^ ((mr & 3) << 3);
    ushort* ablk = adjp + (size_t)((b*64 + rowblk)*8 + ks) * 18432;

    int sp  = tid >> 4;
    int sk0 = (tid & 15) * 2;
    const ushort* tbase = Tin + ((size_t)(b*16 + sp)*1024 + (size_t)ks*128) * 16;

    int g   = lane >> 4;
    int c15 = lane & 15;
    int gx  = (g ^ (c15 & 3)) * 8;

    f32x4 acc[4];
    #pragma unroll
    for (int j = 0; j < 4; j++) acc[j] = (f32x4){0.f, 0.f, 0.f, 0.f};

    for (int chunk = 0; chunk < 4; chunk++) {
        float lo[9], hi[9];
        if constexpr (PACK) {
            #pragma unroll
            for (int a = 0; a < A_; a++) {
                float2 v = *(const float2*)&adjf[(((size_t)b*A_ + a)*N_ + (n0+mr))*N_
                                                 + ks*128 + chunk*32 + mk2];
                lo[a] = v.x; hi[a] = v.y;
            }
        } else {
            #pragma unroll
            for (int a = 0; a < A_; a++) {
                uint av = *(const uint*)&ablk[chunk*4608 + (a*16 + mr)*32 + mk2];
                lo[a] = bflo(av); hi[a] = bfhi(av);
            }
        }
        const ushort* tsl = tbase + (size_t)(chunk*32 + sk0) * 16;
        uint4 q0 = *(const uint4*)(tsl + 0);
        uint4 q1 = *(const uint4*)(tsl + 8);
        uint4 q2 = *(const uint4*)(tsl + 16);
        uint4 q3 = *(const uint4*)(tsl + 24);

        if constexpr (PACK) {
            #pragma unroll
            for (int a = 0; a < A_; a++)
                *(uint*)&ablk[chunk*4608 + (a*16 + mr)*32 + mk2] = pack2_bf(lo[a], hi[a]);
        }

        if (chunk) __syncthreads();

        #pragma unroll
        for (int h = 0; h < H_; h++) {
            float s0 = soft_s[h][0]*lo[0];
            float s1 = soft_s[h][0]*hi[0];
            #pragma unroll
            for (int a = 1; a < A_; a++) { s0 += soft_s[h][a]*lo[a]; s1 += soft_s[h][a]*hi[a]; }
            *(uint*)&sm_ms[h*640 + mr*40 + mk2s] = pack2_bf(s0, s1);
        }
        {
            uint l0[4] = {q0.x, q0.y, q0.z, q0.w};
            uint l1[4] = {q1.x, q1.y, q1.z, q1.w};
            uint h0[4] = {q2.x, q2.y, q2.z, q2.w};
            uint h1[4] = {q3.x, q3.y, q3.z, q3.w};
            #pragma unroll
            for (int ci = 0; ci < 8; ci++) {
                uint a0 = (l0[ci>>1] >> ((ci&1)*16)) & 0xffffu;
                uint b0 = (h0[ci>>1] >> ((ci&1)*16)) & 0xffffu;
                int k0s = sk0 ^ ((ci & 3) << 3);
                *(uint*)&sm_t[sp*648 + ci*40 + k0s] = a0 | (b0 << 16);
            }
            #pragma unroll
            for (int ci = 0; ci < 8; ci++) {
                int c = ci + 8;
                uint a0 = (l1[ci>>1] >> ((ci&1)*16)) & 0xffffu;
                uint b0 = (h1[ci>>1] >> ((ci&1)*16)) & 0xffffu;
                int k0s = sk0 ^ ((c & 3) << 3);
                *(uint*)&sm_t[sp*648 + c*40 + k0s] = a0 | (b0 << 16);
            }
        }
        __syncthreads();

        {
            const ushort* mb = sm_ms + c15*40 + gx;
            const ushort* tb = sm_t  + c15*40 + gx;
            #pragma unroll
            for (int j = 0; j < 4; j++) {
                int cg = w + 4*j;
                int h  = cg >> 1;
                bf16x8 af  = *(const bf16x8*)&mb[h*640];
                bf16x8 bfr = *(const bf16x8*)&tb[cg*648];
                acc[j] = __builtin_amdgcn_mfma_f32_16x16x32_bf16(af, bfr, acc[j], 0, 0, 0);
            }
        }
    }

    __syncthreads();
    float* Ep = (float*)smem;
    #pragma unroll
    for (int j = 0; j < 4; j++) {
        int cg = w + 4*j;
        #pragma unroll
        for (int i = 0; i < 4; i++)
            Ep[cg*256 + (g*4 + i)*16 + c15] = acc[j][i];
    }
    __syncthreads();
    {
        int p = tid >> 4, r = tid & 15;
        float* dst = Pp + (((size_t)(ks*B_ + b)*16 + p)*N_ + (n0 + r)) * 16;
        const float* src = &Ep[p*256 + r*16];
        *(float4*)&dst[0]  = *(const float4*)&src[0];
        *(float4*)&dst[4]  = *(const float4*)&src[4];
        *(float4*)&dst[8]  = *(const float4*)&src[8];
        *(float4*)&dst[12] = *(const float4*)&src[12];
    }
}

// ---------------- reduce KS_ slabs -> bf16 T panels ----------------
__global__ void chain_reduce(const float* __restrict__ Pp, ushort* __restrict__ outp)
{
    int pidx = blockIdx.x * 256 + threadIdx.x;
    float4 s = make_float4(0.f, 0.f, 0.f, 0.f);
    #pragma unroll
    for (int ks = 0; ks < KS_; ks++) {
        float4 v = ((const float4*)Pp)[(size_t)ks*SLABF4_ + pidx];
        s.x += v.x; s.y += v.y; s.z += v.z; s.w += v.w;
    }
    uint2 wv;
    wv.x = pack2_bf(s.x, s.y);
    wv.y = pack2_bf(s.z, s.w);
    ((uint2*)outp)[pidx] = wv;
}

// ---------------- V projection (SIMT, writes bf16 panels) ----------------
#define BK 16
__global__ void gemm_v(const float* __restrict__ A, const float* __restrict__ Bm,
                       const float* __restrict__ bias, ushort* __restrict__ C)
{
    __shared__ __align__(16) float As[BK][68];
    __shared__ __align__(16) float Bs[BK][68];
    int m0 = blockIdx.x * 64;
    int n0 = blockIdx.y * 64;
    int tid = threadIdx.x;
    int tx = tid & 15, ty = tid >> 4;

    float acc[4][4];
    #pragma unroll
    for (int i = 0; i < 4; i++)
        #pragma unroll
        for (int j = 0; j < 4; j++) acc[i][j] = 0.0f;

    for (int k0 = 0; k0 < D_; k0 += BK) {
        {
            int m = tid >> 2;
            int k = (tid & 3) * 4;
            float4 v = *(const float4*)&A[(size_t)(m0+m)*D_ + k0 + k];
            As[k+0][m] = v.x; As[k+1][m] = v.y; As[k+2][m] = v.z; As[k+3][m] = v.w;
        }
        {
            int k = tid >> 4;
            int n = (tid & 15) * 4;
            int c = n0 + n; int h = c >> 5; int ee = c & 31;
            float4 v = *(const float4*)&Bm[(size_t)h*D_*DH_ + (size_t)(k0+k)*DH_ + ee];
            *(float4*)&Bs[k][n] = v;
        }
        __syncthreads();
        #pragma unroll
        for (int k = 0; k < BK; k++) {
            float4 a4 = *(const float4*)&As[k][ty*4];
            float4 b4 = *(const float4*)&Bs[k][tx*4];
            acc[0][0] += a4.x*b4.x; acc[0][1] += a4.x*b4.y; acc[0][2] += a4.x*b4.z; acc[0][3] += a4.x*b4.w;
            acc[1][0] += a4.y*b4.x; acc[1][1] += a4.y*b4.y; acc[1][2] += a4.y*b4.z; acc[1][3] += a4.y*b4.w;
            acc[2][0] += a4.z*b4.x; acc[2][1] += a4.z*b4.y; acc[2][2] += a4.z*b4.z; acc[2][3] += a4.z*b4.w;
            acc[3][0] += a4.w*b4.x; acc[3][1] += a4.w*b4.y; acc[3][2] += a4.w*b4.z; acc[3][3] += a4.w*b4.w;
        }
        __syncthreads();
    }

    #pragma unroll
    for (int i = 0; i < 4; i++) {
        int row  = m0 + ty*4 + i;
        int nloc = n0 + tx*4;
        float o[4];
        #pragma unroll
        for (int j = 0; j < 4; j++) {
            int c = nloc + j;
            int h = c >> 5, ee = c & 31, n = row & (N_-1);
            o[j] = acc[i][j] + bias[(size_t)h*N_*DH_ + (size_t)n*DH_ + ee];
        }
        int bb = row >> 10, n = row & (N_-1);
        int cg = nloc >> 4, cc = nloc & 15;
        uint2 wv;
        wv.x = pack2_bf(o[0], o[1]);
        wv.y = pack2_bf(o[2], o[3]);
        *(uint2*)&C[(((size_t)bb*16 + cg)*N_ + n)*16 + cc] = wv;
    }
}

// ================= FFN tail: BM=8, grid 256 (1+ block per CU), 256 threads =================
// MFMA A-rows 8..15 are garbage and never stored (half-waste is free: MFMA is ~0.5% utilized).

// ---- gemm_r: attn(=sum Pp slabs * invd) @ W0 + x -> resid(fp32 global); h=LN -> hbuf(bf16) ----
__global__ __launch_bounds__(256, 4)
void gemm_r(const float* __restrict__ Pp, const float* __restrict__ invd,
            const float* __restrict__ W0, const float* __restrict__ x,
            const float* __restrict__ gamma, const float* __restrict__ beta,
            float* __restrict__ resid, ushort* __restrict__ hbuf)
{
    __shared__ __align__(16) ushort As[16*40];
    __shared__ __align__(16) ushort Bs[256*40];
    __shared__ float lnb[8*257];
    __shared__ float2 stat[8];

    int m0 = blockIdx.x * 8;
    int b  = m0 >> 10;
    int nb = m0 & (N_-1);
    int tid = threadIdx.x;
    int lane = tid & 63;
    int w = tid >> 6;
    int g = lane >> 4, c15 = lane & 15;
    int gx = (g ^ (c15 & 3)) * 8;

    int am  = tid >> 4;               // 0..7 valid when tid<128
    int ak2 = (tid & 15) * 2;
    int apos = am*40 + ((((ak2>>3) ^ (am&3))) << 3) + (ak2 & 7);
    float idv = (tid < 128) ? invd[b*N_ + nb + am] : 0.f;

    int bn8 = (tid & 31) * 8;
    int bkq = (tid >> 5) * 4;
    int bposR = ((bkq >> 3) << 3) + (bkq & 7);

    f32x4 acc[4];
    #pragma unroll
    for (int j = 0; j < 4; j++) acc[j] = (f32x4){0.f,0.f,0.f,0.f};

    for (int ksi = 0; ksi < 8; ksi++) {
        int k0 = ksi * 32;
        uint av = 0;
        if (tid < 128) {
            int k = k0 + ak2;
            size_t base = (((size_t)(b*16 + (k>>4)))*N_ + nb + am)*16 + (k & 15);
            float s0 = 0.f, s1 = 0.f;
            #pragma unroll
            for (int sl = 0; sl < 8; sl++) {
                float2 v = *(const float2*)&Pp[(size_t)sl*SLABF_ + base];
                s0 += v.x; s1 += v.y;
            }
            av = pack2_bf(s0*idv, s1*idv);
        }
        float4 lo[4], hi[4];
        #pragma unroll
        for (int i = 0; i < 4; i++) {
            lo[i] = *(const float4*)&W0[(size_t)(k0+bkq+i)*D_ + bn8];
            hi[i] = *(const float4*)&W0[(size_t)(k0+bkq+i)*D_ + bn8 + 4];
        }
        if (ksi) __syncthreads();
        if (tid < 128) *(uint*)&As[apos] = av;
        #pragma unroll
        for (int jn = 0; jn < 8; jn++) {
            int n = bn8 + jn;
            float v0 = (jn<4)? ((const float*)&lo[0])[jn] : ((const float*)&hi[0])[jn-4];
            float v1 = (jn<4)? ((const float*)&lo[1])[jn] : ((const float*)&hi[1])[jn-4];
            float v2 = (jn<4)? ((const float*)&lo[2])[jn] : ((const float*)&hi[2])[jn-4];
            float v3 = (jn<4)? ((const float*)&lo[3])[jn] : ((const float*)&hi[3])[jn-4];
            uint2 wv; wv.x = pack2_bf(v0, v1); wv.y = pack2_bf(v2, v3);
            *(uint2*)&Bs[n*40 + (bposR ^ ((n&3)<<3))] = wv;
        }
        __syncthreads();
        const ushort* ab = As + c15*40 + gx;
        #pragma unroll
        for (int nt = 0; nt < 4; nt++) {
            int n = w*64 + nt*16 + c15;
            bf16x8 af  = *(const bf16x8*)ab;
            bf16x8 bfr = *(const bf16x8*)&Bs[n*40 + gx];
            acc[nt] = __builtin_amdgcn_mfma_f32_16x16x32_bf16(af, bfr, acc[nt], 0, 0, 0);
        }
    }
    __syncthreads();

    if (g < 2) {
        #pragma unroll
        for (int nt = 0; nt < 4; nt++) {
            int c = w*64 + nt*16 + c15;
            #pragma unroll
            for (int i = 0; i < 4; i++) {
                int r = g*4 + i;
                lnb[r*257 + c] = acc[nt][i] + x[(size_t)(m0+r)*D_ + c];
            }
        }
    }
    __syncthreads();
    if (tid < 128) {
        int rr = tid >> 4, sl = tid & 15;
        float sum = 0.f, sq = 0.f;
        #pragma unroll
        for (int j = 0; j < 16; j++) {
            float v = lnb[rr*257 + sl + 16*j];
            sum += v; sq += v*v;
        }
        #pragma unroll
        for (int m = 1; m < 16; m <<= 1) { sum += __shfl_xor(sum, m); sq += __shfl_xor(sq, m); }
        if (sl == 0) {
            float mean = sum * (1.0f/D_);
            float var  = fmaxf(sq * (1.0f/D_) - mean*mean, 0.f);
            stat[rr] = make_float2(mean, rsqrtf(var + 1e-12f));
        }
    }
    __syncthreads();
    if (tid < 128) {
        int rr = tid & 7, s2 = tid >> 3;     // 16 col-groups of 16
        float2 ms = stat[rr];
        int c0 = s2 * 16;
        uint hw[8];
        #pragma unroll
        for (int q = 0; q < 4; q++) {
            int c = c0 + q*4;
            float4 v = *(const float4*)&lnb[rr*257 + c];
            *(float4*)&resid[(size_t)(m0+rr)*D_ + c] = v;
            float4 gm = *(const float4*)&gamma[c];
            float4 bt = *(const float4*)&beta[c];
            float h0 = (v.x - ms.x)*ms.y*gm.x + bt.x;
            float h1 = (v.y - ms.x)*ms.y*gm.y + bt.y;
            float h2 = (v.z - ms.x)*ms.y*gm.z + bt.z;
            float h3 = (v.w - ms.x)*ms.y*gm.w + bt.w;
            hw[2*q]   = pack2_bf(h0, h1);
            hw[2*q+1] = pack2_bf(h2, h3);
        }
        ushort* hp = &hbuf[(size_t)(m0+rr)*D_ + c0];
        *(uint4*)&hp[0] = make_uint4(hw[0], hw[1], hw[2], hw[3]);
        *(uint4*)&hp[8] = make_uint4(hw[4], hw[5], hw[6], hw[7]);
    }
}

// ---- gemm_f1: f = LN(gelu(h@W1 + b1), gf, bf) -> bf16 global ----
__global__ __launch_bounds__(256, 2)
void gemm_f1(const ushort* __restrict__ hbuf, const float* __restrict__ W1,
             const float* __restrict__ b1, const float* __restrict__ gf,
             const float* __restrict__ bfv, ushort* __restrict__ fout)
{
    __shared__ __align__(16) ushort As[16*40];
    __shared__ __align__(16) ushort Bs[512*40];
    __shared__ float lnb[8*513];
    __shared__ float2 stat[8];

    int m0 = blockIdx.x * 8;
    int tid = threadIdx.x;
    int lane = tid & 63;
    int w = tid >> 6;
    int g = lane >> 4, c15 = lane & 15;
    int gx = (g ^ (c15 & 3)) * 8;

    int am  = tid >> 4;
    int ak2 = (tid & 15) * 2;
    int apos = am*40 + ((((ak2>>3) ^ (am&3))) << 3) + (ak2 & 7);
    int bn8 = (tid & 63) * 8;
    int bk8 = (tid >> 6) * 8;

    f32x4 acc1[8];
    #pragma unroll
    for (int j = 0; j < 8; j++) acc1[j] = (f32x4){0.f,0.f,0.f,0.f};

    for (int ksi = 0; ksi < 8; ksi++) {
        int k0 = ksi * 32;
        uint av = 0;
        if (tid < 128) av = *(const uint*)&hbuf[(size_t)(m0+am)*D_ + k0 + ak2];
        float4 q[16];
        #pragma unroll
        for (int i = 0; i < 8; i++) {
            q[2*i]   = *(const float4*)&W1[(size_t)(k0+bk8+i)*(2*D_) + bn8];
            q[2*i+1] = *(const float4*)&W1[(size_t)(k0+bk8+i)*(2*D_) + bn8 + 4];
        }
        if (ksi) __syncthreads();
        if (tid < 128) *(uint*)&As[apos] = av;
        #pragma unroll
        for (int jn = 0; jn < 8; jn++) {
            int n = bn8 + jn;
            float e0 = (jn<4)? ((const float*)&q[0])[jn]  : ((const float*)&q[1])[jn-4];
            float e1 = (jn<4)? ((const float*)&q[2])[jn]  : ((const float*)&q[3])[jn-4];
            float e2 = (jn<4)? ((const float*)&q[4])[jn]  : ((const float*)&q[5])[jn-4];
            float e3 = (jn<4)? ((const float*)&q[6])[jn]  : ((const float*)&q[7])[jn-4];
            float e4 = (jn<4)? ((const float*)&q[8])[jn]  : ((const float*)&q[9])[jn-4];
            float e5 = (jn<4)? ((const float*)&q[10])[jn] : ((const float*)&q[11])[jn-4];
            float e6 = (jn<4)? ((const float*)&q[12])[jn] : ((const float*)&q[13])[jn-4];
            float e7 = (jn<4)? ((const float*)&q[14])[jn] : ((const float*)&q[15])[jn-4];
            uint4 wv;
            wv.x = pack2_bf(e0, e1); wv.y = pack2_bf(e2, e3);
            wv.z = pack2_bf(e4, e5); wv.w = pack2_bf(e6, e7);
            *(uint4*)&Bs[n*40 + ((((bk8>>3) ^ (n&3))) << 3)] = wv;
        }
        __syncthreads();
        const ushort* ab = As + c15*40 + gx;
        #pragma unroll
        for (int nt = 0; nt < 8; nt++) {
            int n = w*128 + nt*16 + c15;
            bf16x8 af  = *(const bf16x8*)ab;
            bf16x8 bfr = *(const bf16x8*)&Bs[n*40 + gx];
            acc1[nt] = __builtin_amdgcn_mfma_f32_16x16x32_bf16(af, bfr, acc1[nt], 0, 0, 0);
        }
    }
    __syncthreads();

    if (g < 2) {
        #pragma unroll
        for (int nt = 0; nt < 8; nt++) {
            int c = w*128 + nt*16 + c15;
            float bias = b1[c];
            #pragma unroll
            for (int i = 0; i < 4; i++) {
                int r = g*4 + i;
                float v = acc1[nt][i] + bias;
                v = 0.5f * v * (1.0f + erff(v * 0.70710678118654752f));
                lnb[r*513 + c] = v;
            }
        }
    }
    __syncthreads();
    if (tid < 128) {
        int rr = tid >> 4, sl = tid & 15;
        float sum = 0.f, sq = 0.f;
        #pragma unroll
        for (int j = 0; j < 32; j++) {
            float v = lnb[rr*513 + sl + 16*j];
            sum += v; sq += v*v;
        }
        #pragma unroll
        for (int m = 1; m < 16; m <<= 1) { sum += __shfl_xor(sum, m); sq += __shfl_xor(sq, m); }
        if (sl == 0) {
            float mean = sum * (1.0f/(2*D_));
            float var  = fmaxf(sq * (1.0f/(2*D_)) - mean*mean, 0.f);
            stat[rr] = make_float2(mean, rsqrtf(var + 1e-12f));
        }
    }
    __syncthreads();
    if (tid < 128) {
        int rr = tid & 7, s2 = tid >> 3;     // 16 col-groups of 32
        float2 ms = stat[rr];
        int c0 = s2 * 32;
        #pragma unroll
        for (int q = 0; q < 8; q++) {
            int c = c0 + q*4;
            float4 v = *(const float4*)&lnb[rr*513 + c];
            float4 gm = *(const float4*)&gf[c];
            float4 bt = *(const float4*)&bfv[c];
            float h0 = (v.x - ms.x)*ms.y*gm.x + bt.x;
            float h1 = (v.y - ms.x)*ms.y*gm.y + bt.y;
            float h2 = (v.z - ms.x)*ms.y*gm.z + bt.z;
            float h3 = (v.w - ms.x)*ms.y*gm.w + bt.w;
            *(uint2*)&fout[(size_t)(m0+rr)*(2*D_) + c] = make_uint2(pack2_bf(h0,h1), pack2_bf(h2,h3));
        }
    }
}

// ---- gemm_f2: out = f@W2 + b2f + resid ----
__global__ __launch_bounds__(256, 4)
void gemm_f2(const ushort* __restrict__ fbuf, const float* __restrict__ W2,
             const float* __restrict__ b2f, const float* __restrict__ resid,
             float* __restrict__ outp)
{
    __shared__ __align__(16) ushort As[16*40];
    __shared__ __align__(16) ushort Bs[256*40];
    __shared__ float esc[8*257];

    int m0 = blockIdx.x * 8;
    int tid = threadIdx.x;
    int lane = tid & 63;
    int w = tid >> 6;
    int g = lane >> 4, c15 = lane & 15;
    int gx = (g ^ (c15 & 3)) * 8;

    int am  = tid >> 4;
    int ak2 = (tid & 15) * 2;
    int apos = am*40 + ((((ak2>>3) ^ (am&3))) << 3) + (ak2 & 7);
    int bn8 = (tid & 31) * 8;
    int bkq = (tid >> 5) * 4;
    int bposR = ((bkq >> 3) << 3) + (bkq & 7);

    f32x4 acc[4];
    #pragma unroll
    for (int j = 0; j < 4; j++) acc[j] = (f32x4){0.f,0.f,0.f,0.f};

    for (int ksi = 0; ksi < 16; ksi++) {
        int k0 = ksi * 32;
        uint av = 0;
        if (tid < 128) av = *(const uint*)&fbuf[(size_t)(m0+am)*(2*D_) + k0 + ak2];
        float4 lo[4], hi[4];
        #pragma unroll
        for (int i = 0; i < 4; i++) {
            lo[i] = *(const float4*)&W2[(size_t)(k0+bkq+i)*D_ + bn8];
            hi[i] = *(const float4*)&W2[(size_t)(k0+bkq+i)*D_ + bn8 + 4];
        }
        if (ksi) __syncthreads();
        if (tid < 128) *(uint*)&As[apos] = av;
        #pragma unroll
        for (int jn = 0; jn < 8; jn++) {
            int n = bn8 + jn;
            float v0 = (jn<4)? ((const float*)&lo[0])[jn] : ((const float*)&hi[0])[jn-4];
            float v1 = (jn<4)? ((const float*)&lo[1])[jn] : ((const float*)&hi[1])[jn-4];
            float v2 = (jn<4)? ((const float*)&lo[2])[jn] : ((const float*)&hi[2])[jn-4];
            float v3 = (jn<4)? ((const float*)&lo[3])[jn] : ((const float*)&hi[3])[jn-4];
            uint2 wv; wv.x = pack2_bf(v0, v1); wv.y = pack2_bf(v2, v3);
            *(uint2*)&Bs[n*40 + (bposR ^ ((n&3)<<3))] = wv;
        }
        __syncthreads();
        const ushort* ab = As + c15*40 + gx;
        #pragma unroll
        for (int nt = 0; nt < 4; nt++) {
            int n = w*64 + nt*16 + c15;
            bf16x8 af  = *(const bf16x8*)ab;
            bf16x8 bfr = *(const bf16x8*)&Bs[n*40 + gx];
            acc[nt] = __builtin_amdgcn_mfma_f32_16x16x32_bf16(af, bfr, acc[nt], 0, 0, 0);
        }
    }
    __syncthreads();

    if (g < 2) {
        #pragma unroll
        for (int nt = 0; nt < 4; nt++) {
            int c = w*64 + nt*16 + c15;
            #pragma unroll
            for (int i = 0; i < 4; i++)
                esc[(g*4+i)*257 + c] = acc[nt][i];
        }
    }
    __syncthreads();
    if (tid < 128) {
        int rr = tid & 7, s2 = tid >> 3;
        int c0 = s2 * 16;
        #pragma unroll
        for (int q = 0; q < 4; q++) {
            int c = c0 + q*4;
            float4 v  = *(const float4*)&esc[rr*257 + c];
            float4 bb = *(const float4*)&b2f[c];
            float4 rs = *(const float4*)&resid[(size_t)(m0+rr)*D_ + c];
            float4 o = make_float4(v.x+bb.x+rs.x, v.y+bb.y+rs.y, v.z+bb.z+rs.z, v.w+bb.w+rs.w);
            *(float4*)&outp[(size_t)(m0+rr)*D_ + c] = o;
        }
    }
}

extern "C" void kernel_launch(void* const* d_in, const int* in_sizes, int n_in,
                              void* d_out, int out_size, void* d_ws, size_t ws_size,
                              hipStream_t stream)
{
    const float* adj    = (const float*)d_in[0];
    const float* degree = (const float*)d_in[1];
    const float* x      = (const float*)d_in[2];
    const float* kern   = (const float*)d_in[3];
    const float* Wv     = (const float*)d_in[4];
    const float* Bv     = (const float*)d_in[5];
    const float* W0     = (const float*)d_in[6];
    const float* gamma2 = (const float*)d_in[7];
    const float* beta2  = (const float*)d_in[8];
    const float* W1     = (const float*)d_in[9];
    const float* b1     = (const float*)d_in[10];
    const float* gf     = (const float*)d_in[11];
    const float* bf_    = (const float*)d_in[12];
    const float* W2     = (const float*)d_in[13];
    const float* b2f    = (const float*)d_in[14];
    float* out = (float*)d_out;
    float* ws  = (float*)d_ws;

    size_t off = 0;
    float* soft  = ws + off; off += 512;
    float* invd  = ws + off; off += 2048;
    float* T0    = ws + off; off += (size_t)ROWS_*D_;       // bf16 panels
    float* T1    = ws + off; off += (size_t)ROWS_*D_;
    float* resid = ws + off; off += (size_t)ROWS_*D_;       // fp32
    float* hbufF = ws + off; off += (size_t)ROWS_*D_/2;     // bf16
    float* foutF = ws + off; off += (size_t)ROWS_*D_;       // bf16 (2D cols)
    float* Pp    = ws + off; off += (size_t)KS_*ROWS_*D_;   // 16.8MB fp32 slabs
    ushort* adjp = (ushort*)(ws + off);                      // 37.75MB bf16

    ushort* T0b = (ushort*)T0;
    ushort* T1b = (ushort*)T1;
    ushort* hb  = (ushort*)hbufF;
    ushort* fb  = (ushort*)foutF;

    prep_kernel<<<9, 256, 0, stream>>>(kern, degree, soft, invd);
    gemm_v<<<dim3(ROWS_/64, D_/64), 256, 0, stream>>>(x, Wv, Bv, T0b);

    int chain_grid  = B_*64*KS_;    // 1024
    int reduce_grid = SLABF4_/256;  // 512
    chain_mfma<1><<<chain_grid, 256, 0, stream>>>(adj, adjp, soft, T0b, Pp, 3);
    chain_reduce<<<reduce_grid, 256, 0, stream>>>(Pp, T1b);
    chain_mfma<0><<<chain_grid, 256, 0, stream>>>(adj, adjp, soft, T1b, Pp, 2);
    chain_reduce<<<reduce_grid, 256, 0, stream>>>(Pp, T0b);
    chain_mfma<0><<<chain_grid, 256, 0, stream>>>(adj, adjp, soft, T0b, Pp, 1);
    chain_reduce<<<reduce_grid, 256, 0, stream>>>(Pp, T1b);
    chain_mfma<0><<<chain_grid, 256, 0, stream>>>(adj, adjp, soft, T1b, Pp, 0);

    gemm_r <<<ROWS_/8, 256, 0, stream>>>(Pp, invd, W0, x, gamma2, beta2, resid, hb);
    gemm_f1<<<ROWS_/8, 256, 0, stream>>>(hb, W1, b1, gf, bf_, fb);
    gemm_f2<<<ROWS_/8, 256, 0, stream>>>(fb, W2, b2f, resid, out);
}

// Round 11
// 166.211 us; speedup vs baseline: 3.8426x; 1.0989x over previous
//
#include <hip/hip_runtime.h>
#include <hip/hip_bf16.h>
#include <math.h>

#define B_ 2
#define A_ 9
#define N_ 1024
#define P_ 4
#define D_ 256
#define H_ 8
#define DH_ 32
#define ROWS_ (B_*N_)   // 2048
#define KS_ 8           // K-split factor for chain (k-slice 128)
#define SLABU_ 524288   // Pp slab stride in ushorts (2*16*1024*16)
#define SLABU2_ 131072  // Pp slab stride in uint2 (4 bf16 each)

typedef __attribute__((ext_vector_type(8))) short bf16x8;
typedef __attribute__((ext_vector_type(4))) float f32x4;

__device__ __forceinline__ uint pack2_bf(float x, float y) {
    uint ux = __float_as_uint(x); ux += 0x7fffu + ((ux >> 16) & 1u);
    uint uy = __float_as_uint(y); uy += 0x7fffu + ((uy >> 16) & 1u);
    return (ux >> 16) | (uy & 0xffff0000u);
}
__device__ __forceinline__ float bflo(uint u){ return __uint_as_float(u << 16); }
__device__ __forceinline__ float bfhi(uint u){ return __uint_as_float(u & 0xffff0000u); }

// ---------------- MFMA chain step. PACK=1: read fp32 adjacency + write bf16 adjp slab ----------------
// soft = softmax(relu(kernels)) computed IN-BLOCK (identical across blocks; removes prep kernel).
// Pp partial slabs are bf16 (halves slab traffic; sum done in fp32 at the consumer).
template<int PACK>
__global__ __launch_bounds__(256, 4)
void chain_mfma(const float* __restrict__ adjf, ushort* __restrict__ adjp,
                const float* __restrict__ kern,
                const ushort* __restrict__ Tin, ushort* __restrict__ Pp, int step)
{
    __shared__ __align__(16) ushort smem[8*640 + 16*648];
    __shared__ float soft_s[8][9];
    ushort* sm_ms = smem;
    ushort* sm_t  = smem + 8*640;

    int bid    = blockIdx.x;
    int ks     = bid & (KS_-1);
    int rowblk = (bid >> 3) & 63;
    int b      = bid >> 9;
    int n0     = rowblk * 16;
    int tid    = threadIdx.x;
    int lane   = tid & 63;
    int w      = tid >> 6;

    if (tid < 8) {
        int h = tid;
        float vals[A_];
        float m = 0.0f;
        #pragma unroll
        for (int a = 0; a < A_; a++) {
            float v = kern[h*A_*P_ + a*P_ + step];
            v = v > 0.0f ? v : 0.0f;
            vals[a] = v;
            m = fmaxf(m, v);
        }
        float s = 0.0f;
        #pragma unroll
        for (int a = 0; a < A_; a++) { vals[a] = expf(vals[a] - m); s += vals[a]; }
        float inv = 1.0f / s;
        #pragma unroll
        for (int a = 0; a < A_; a++) soft_s[h][a] = vals[a] * inv;
    }
    __syncthreads();

    int mr   = tid >> 4;
    int mk2  = (tid & 15) * 2;
    int mk2s = mk2 ^ ((mr & 3) << 3);
    ushort* ablk = adjp + (size_t)((b*64 + rowblk)*8 + ks) * 18432;

    int sp  = tid >> 4;
    int sk0 = (tid & 15) * 2;
    const ushort* tbase = Tin + ((size_t)(b*16 + sp)*1024 + (size_t)ks*128) * 16;

    int g   = lane >> 4;
    int c15 = lane & 15;
    int gx  = (g ^ (c15 & 3)) * 8;

    f32x4 acc[4];
    #pragma unroll
    for (int j = 0; j < 4; j++) acc[j] = (f32x4){0.f, 0.f, 0.f, 0.f};

    for (int chunk = 0; chunk < 4; chunk++) {
        float lo[9], hi[9];
        if constexpr (PACK) {
            #pragma unroll
            for (int a = 0; a < A_; a++) {
                float2 v = *(const float2*)&adjf[(((size_t)b*A_ + a)*N_ + (n0+mr))*N_
                                                 + ks*128 + chunk*32 + mk2];
                lo[a] = v.x; hi[a] = v.y;
            }
        } else {
            #pragma unroll
            for (int a = 0; a < A_; a++) {
                uint av = *(const uint*)&ablk[chunk*4608 + (a*16 + mr)*32 + mk2];
                lo[a] = bflo(av); hi[a] = bfhi(av);
            }
        }
        const ushort* tsl = tbase + (size_t)(chunk*32 + sk0) * 16;
        uint4 q0 = *(const uint4*)(tsl + 0);
        uint4 q1 = *(const uint4*)(tsl + 8);
        uint4 q2 = *(const uint4*)(tsl + 16);
        uint4 q3 = *(const uint4*)(tsl + 24);

        if constexpr (PACK) {
            #pragma unroll
            for (int a = 0; a < A_; a++)
                *(uint*)&ablk[chunk*4608 + (a*16 + mr)*32 + mk2] = pack2_bf(lo[a], hi[a]);
        }

        if (chunk) __syncthreads();

        #pragma unroll
        for (int h = 0; h < H_; h++) {
            float s0 = soft_s[h][0]*lo[0];
            float s1 = soft_s[h][0]*hi[0];
            #pragma unroll
            for (int a = 1; a < A_; a++) { s0 += soft_s[h][a]*lo[a]; s1 += soft_s[h][a]*hi[a]; }
            *(uint*)&sm_ms[h*640 + mr*40 + mk2s] = pack2_bf(s0, s1);
        }
        {
            uint l0[4] = {q0.x, q0.y, q0.z, q0.w};
            uint l1[4] = {q1.x, q1.y, q1.z, q1.w};
            uint h0[4] = {q2.x, q2.y, q2.z, q2.w};
            uint h1[4] = {q3.x, q3.y, q3.z, q3.w};
            #pragma unroll
            for (int ci = 0; ci < 8; ci++) {
                uint a0 = (l0[ci>>1] >> ((ci&1)*16)) & 0xffffu;
                uint b0 = (h0[ci>>1] >> ((ci&1)*16)) & 0xffffu;
                int k0s = sk0 ^ ((ci & 3) << 3);
                *(uint*)&sm_t[sp*648 + ci*40 + k0s] = a0 | (b0 << 16);
            }
            #pragma unroll
            for (int ci = 0; ci < 8; ci++) {
                int c = ci + 8;
                uint a0 = (l1[ci>>1] >> ((ci&1)*16)) & 0xffffu;
                uint b0 = (h1[ci>>1] >> ((ci&1)*16)) & 0xffffu;
                int k0s = sk0 ^ ((c & 3) << 3);
                *(uint*)&sm_t[sp*648 + c*40 + k0s] = a0 | (b0 << 16);
            }
        }
        __syncthreads();

        {
            const ushort* mb = sm_ms + c15*40 + gx;
            const ushort* tb = sm_t  + c15*40 + gx;
            #pragma unroll
            for (int j = 0; j < 4; j++) {
                int cg = w + 4*j;
                int h  = cg >> 1;
                bf16x8 af  = *(const bf16x8*)&mb[h*640];
                bf16x8 bfr = *(const bf16x8*)&tb[cg*648];
                acc[j] = __builtin_amdgcn_mfma_f32_16x16x32_bf16(af, bfr, acc[j], 0, 0, 0);
            }
        }
    }

    __syncthreads();
    float* Ep = (float*)smem;
    #pragma unroll
    for (int j = 0; j < 4; j++) {
        int cg = w + 4*j;
        #pragma unroll
        for (int i = 0; i < 4; i++)
            Ep[cg*256 + (g*4 + i)*16 + c15] = acc[j][i];
    }
    __syncthreads();
    {
        int p = tid >> 4, r = tid & 15;
        ushort* dst = Pp + (((size_t)(ks*B_ + b)*16 + p)*N_ + (n0 + r)) * 16;
        const float* src = &Ep[p*256 + r*16];
        uint u0 = pack2_bf(src[0],  src[1]);
        uint u1 = pack2_bf(src[2],  src[3]);
        uint u2 = pack2_bf(src[4],  src[5]);
        uint u3 = pack2_bf(src[6],  src[7]);
        uint u4 = pack2_bf(src[8],  src[9]);
        uint u5 = pack2_bf(src[10], src[11]);
        uint u6 = pack2_bf(src[12], src[13]);
        uint u7 = pack2_bf(src[14], src[15]);
        *(uint4*)&dst[0] = make_uint4(u0,u1,u2,u3);
        *(uint4*)&dst[8] = make_uint4(u4,u5,u6,u7);
    }
}

// ---------------- reduce KS_ bf16 slabs -> bf16 T panels (fp32 accumulate) ----------------
__global__ void chain_reduce(const ushort* __restrict__ Pp, ushort* __restrict__ outp)
{
    int pidx = blockIdx.x * 256 + threadIdx.x;   // one uint2 (4 bf16) per thread
    float4 s = make_float4(0.f, 0.f, 0.f, 0.f);
    #pragma unroll
    for (int ks = 0; ks < KS_; ks++) {
        uint2 v = ((const uint2*)Pp)[(size_t)ks*SLABU2_ + pidx];
        s.x += bflo(v.x); s.y += bfhi(v.x);
        s.z += bflo(v.y); s.w += bfhi(v.y);
    }
    uint2 wv;
    wv.x = pack2_bf(s.x, s.y);
    wv.y = pack2_bf(s.z, s.w);
    ((uint2*)outp)[pidx] = wv;
}

// ---------------- V projection (SIMT, writes bf16 panels) ----------------
#define BK 16
__global__ void gemm_v(const float* __restrict__ A, const float* __restrict__ Bm,
                       const float* __restrict__ bias, ushort* __restrict__ C)
{
    __shared__ __align__(16) float As[BK][68];
    __shared__ __align__(16) float Bs[BK][68];
    int m0 = blockIdx.x * 64;
    int n0 = blockIdx.y * 64;
    int tid = threadIdx.x;
    int tx = tid & 15, ty = tid >> 4;

    float acc[4][4];
    #pragma unroll
    for (int i = 0; i < 4; i++)
        #pragma unroll
        for (int j = 0; j < 4; j++) acc[i][j] = 0.0f;

    for (int k0 = 0; k0 < D_; k0 += BK) {
        {
            int m = tid >> 2;
            int k = (tid & 3) * 4;
            float4 v = *(const float4*)&A[(size_t)(m0+m)*D_ + k0 + k];
            As[k+0][m] = v.x; As[k+1][m] = v.y; As[k+2][m] = v.z; As[k+3][m] = v.w;
        }
        {
            int k = tid >> 4;
            int n = (tid & 15) * 4;
            int c = n0 + n; int h = c >> 5; int ee = c & 31;
            float4 v = *(const float4*)&Bm[(size_t)h*D_*DH_ + (size_t)(k0+k)*DH_ + ee];
            *(float4*)&Bs[k][n] = v;
        }
        __syncthreads();
        #pragma unroll
        for (int k = 0; k < BK; k++) {
            float4 a4 = *(const float4*)&As[k][ty*4];
            float4 b4 = *(const float4*)&Bs[k][tx*4];
            acc[0][0] += a4.x*b4.x; acc[0][1] += a4.x*b4.y; acc[0][2] += a4.x*b4.z; acc[0][3] += a4.x*b4.w;
            acc[1][0] += a4.y*b4.x; acc[1][1] += a4.y*b4.y; acc[1][2] += a4.y*b4.z; acc[1][3] += a4.y*b4.w;
            acc[2][0] += a4.z*b4.x; acc[2][1] += a4.z*b4.y; acc[2][2] += a4.z*b4.z; acc[2][3] += a4.z*b4.w;
            acc[3][0] += a4.w*b4.x; acc[3][1] += a4.w*b4.y; acc[3][2] += a4.w*b4.z; acc[3][3] += a4.w*b4.w;
        }
        __syncthreads();
    }

    #pragma unroll
    for (int i = 0; i < 4; i++) {
        int row  = m0 + ty*4 + i;
        int nloc = n0 + tx*4;
        float o[4];
        #pragma unroll
        for (int j = 0; j < 4; j++) {
            int c = nloc + j;
            int h = c >> 5, ee = c & 31, n = row & (N_-1);
            o[j] = acc[i][j] + bias[(size_t)h*N_*DH_ + (size_t)n*DH_ + ee];
        }
        int bb = row >> 10, n = row & (N_-1);
        int cg = nloc >> 4, cc = nloc & 15;
        uint2 wv;
        wv.x = pack2_bf(o[0], o[1]);
        wv.y = pack2_bf(o[2], o[3]);
        *(uint2*)&C[(((size_t)bb*16 + cg)*N_ + n)*16 + cc] = wv;
    }
}

// ================= FFN tail: BM=8, grid 256, 256 threads =================

// ---- gemm_r: attn(=sum bf16 Pp slabs * 1/diag(degree)) @ W0 + x -> resid(fp32); h=LN -> hbuf ----
__global__ __launch_bounds__(256, 4)
void gemm_r(const ushort* __restrict__ Pp, const float* __restrict__ degree,
            const float* __restrict__ W0, const float* __restrict__ x,
            const float* __restrict__ gamma, const float* __restrict__ beta,
            float* __restrict__ resid, ushort* __restrict__ hbuf)
{
    __shared__ __align__(16) ushort As[16*40];
    __shared__ __align__(16) ushort Bs[256*40];
    __shared__ float lnb[8*257];
    __shared__ float2 stat[8];

    int m0 = blockIdx.x * 8;
    int b  = m0 >> 10;
    int nb = m0 & (N_-1);
    int tid = threadIdx.x;
    int lane = tid & 63;
    int w = tid >> 6;
    int g = lane >> 4, c15 = lane & 15;
    int gx = (g ^ (c15 & 3)) * 8;

    int am  = tid >> 4;
    int ak2 = (tid & 15) * 2;
    int apos = am*40 + ((((ak2>>3) ^ (am&3))) << 3) + (ak2 & 7);
    float idv = 0.f;
    if (tid < 128) {
        int n = nb + am;
        idv = 1.0f / degree[((size_t)b*N_ + n)*N_ + n];
    }

    int bn8 = (tid & 31) * 8;
    int bkq = (tid >> 5) * 4;
    int bposR = ((bkq >> 3) << 3) + (bkq & 7);

    f32x4 acc[4];
    #pragma unroll
    for (int j = 0; j < 4; j++) acc[j] = (f32x4){0.f,0.f,0.f,0.f};

    for (int ksi = 0; ksi < 8; ksi++) {
        int k0 = ksi * 32;
        uint av = 0;
        if (tid < 128) {
            int k = k0 + ak2;
            size_t base = (((size_t)(b*16 + (k>>4)))*N_ + nb + am)*16 + (k & 15);
            float s0 = 0.f, s1 = 0.f;
            #pragma unroll
            for (int sl = 0; sl < 8; sl++) {
                uint v = *(const uint*)&Pp[(size_t)sl*SLABU_ + base];
                s0 += bflo(v); s1 += bfhi(v);
            }
            av = pack2_bf(s0*idv, s1*idv);
        }
        float4 lo[4], hi[4];
        #pragma unroll
        for (int i = 0; i < 4; i++) {
            lo[i] = *(const float4*)&W0[(size_t)(k0+bkq+i)*D_ + bn8];
            hi[i] = *(const float4*)&W0[(size_t)(k0+bkq+i)*D_ + bn8 + 4];
        }
        if (ksi) __syncthreads();
        if (tid < 128) *(uint*)&As[apos] = av;
        #pragma unroll
        for (int jn = 0; jn < 8; jn++) {
            int n = bn8 + jn;
            float v0 = (jn<4)? ((const float*)&lo[0])[jn] : ((const float*)&hi[0])[jn-4];
            float v1 = (jn<4)? ((const float*)&lo[1])[jn] : ((const float*)&hi[1])[jn-4];
            float v2 = (jn<4)? ((const float*)&lo[2])[jn] : ((const float*)&hi[2])[jn-4];
            float v3 = (jn<4)? ((const float*)&lo[3])[jn] : ((const float*)&hi[3])[jn-4];
            uint2 wv; wv.x = pack2_bf(v0, v1); wv.y = pack2_bf(v2, v3);
            *(uint2*)&Bs[n*40 + (bposR ^ ((n&3)<<3))] = wv;
        }
        __syncthreads();
        const ushort* ab = As + c15*40 + gx;
        #pragma unroll
        for (int nt = 0; nt < 4; nt++) {
            int n = w*64 + nt*16 + c15;
            bf16x8 af  = *(const bf16x8*)ab;
            bf16x8 bfr = *(const bf16x8*)&Bs[n*40 + gx];
            acc[nt] = __builtin_amdgcn_mfma_f32_16x16x32_bf16(af, bfr, acc[nt], 0, 0, 0);
        }
    }
    __syncthreads();

    if (g < 2) {
        #pragma unroll
        for (int nt = 0; nt < 4; nt++) {
            int c = w*64 + nt*16 + c15;
            #pragma unroll
            for (int i = 0; i < 4; i++) {
                int r = g*4 + i;
                lnb[r*257 + c] = acc[nt][i] + x[(size_t)(m0+r)*D_ + c];
            }
        }
    }
    __syncthreads();
    if (tid < 128) {
        int rr = tid >> 4, sl = tid & 15;
        float sum = 0.f, sq = 0.f;
        #pragma unroll
        for (int j = 0; j < 16; j++) {
            float v = lnb[rr*257 + sl + 16*j];
            sum += v; sq += v*v;
        }
        #pragma unroll
        for (int m = 1; m < 16; m <<= 1) { sum += __shfl_xor(sum, m); sq += __shfl_xor(sq, m); }
        if (sl == 0) {
            float mean = sum * (1.0f/D_);
            float var  = fmaxf(sq * (1.0f/D_) - mean*mean, 0.f);
            stat[rr] = make_float2(mean, rsqrtf(var + 1e-12f));
        }
    }
    __syncthreads();
    if (tid < 128) {
        int rr = tid & 7, s2 = tid >> 3;
        float2 ms = stat[rr];
        int c0 = s2 * 16;
        uint hw[8];
        #pragma unroll
        for (int q = 0; q < 4; q++) {
            int c = c0 + q*4;
            float4 v = *(const float4*)&lnb[rr*257 + c];
            *(float4*)&resid[(size_t)(m0+rr)*D_ + c] = v;
            float4 gm = *(const float4*)&gamma[c];
            float4 bt = *(const float4*)&beta[c];
            float h0 = (v.x - ms.x)*ms.y*gm.x + bt.x;
            float h1 = (v.y - ms.x)*ms.y*gm.y + bt.y;
            float h2 = (v.z - ms.x)*ms.y*gm.z + bt.z;
            float h3 = (v.w - ms.x)*ms.y*gm.w + bt.w;
            hw[2*q]   = pack2_bf(h0, h1);
            hw[2*q+1] = pack2_bf(h2, h3);
        }
        ushort* hp = &hbuf[(size_t)(m0+rr)*D_ + c0];
        *(uint4*)&hp[0] = make_uint4(hw[0], hw[1], hw[2], hw[3]);
        *(uint4*)&hp[8] = make_uint4(hw[4], hw[5], hw[6], hw[7]);
    }
}

// ---- gemm_f1: f = LN(gelu(h@W1 + b1), gf, bf) -> bf16 global ----
__global__ __launch_bounds__(256, 2)
void gemm_f1(const ushort* __restrict__ hbuf, const float* __restrict__ W1,
             const float* __restrict__ b1, const float* __restrict__ gf,
             const float* __restrict__ bfv, ushort* __restrict__ fout)
{
    __shared__ __align__(16) ushort As[16*40];
    __shared__ __align__(16) ushort Bs[512*40];
    __shared__ float lnb[8*513];
    __shared__ float2 stat[8];

    int m0 = blockIdx.x * 8;
    int tid = threadIdx.x;
    int lane = tid & 63;
    int w = tid >> 6;
    int g = lane >> 4, c15 = lane & 15;
    int gx = (g ^ (c15 & 3)) * 8;

    int am  = tid >> 4;
    int ak2 = (tid & 15) * 2;
    int apos = am*40 + ((((ak2>>3) ^ (am&3))) << 3) + (ak2 & 7);
    int bn8 = (tid & 63) * 8;
    int bk8 = (tid >> 6) * 8;

    f32x4 acc1[8];
    #pragma unroll
    for (int j = 0; j < 8; j++) acc1[j] = (f32x4){0.f,0.f,0.f,0.f};

    for (int ksi = 0; ksi < 8; ksi++) {
        int k0 = ksi * 32;
        uint av = 0;
        if (tid < 128) av = *(const uint*)&hbuf[(size_t)(m0+am)*D_ + k0 + ak2];
        float4 q[16];
        #pragma unroll
        for (int i = 0; i < 8; i++) {
            q[2*i]   = *(const float4*)&W1[(size_t)(k0+bk8+i)*(2*D_) + bn8];
            q[2*i+1] = *(const float4*)&W1[(size_t)(k0+bk8+i)*(2*D_) + bn8 + 4];
        }
        if (ksi) __syncthreads();
        if (tid < 128) *(uint*)&As[apos] = av;
        #pragma unroll
        for (int jn = 0; jn < 8; jn++) {
            int n = bn8 + jn;
            float e0 = (jn<4)? ((const float*)&q[0])[jn]  : ((const float*)&q[1])[jn-4];
            float e1 = (jn<4)? ((const float*)&q[2])[jn]  : ((const float*)&q[3])[jn-4];
            float e2 = (jn<4)? ((const float*)&q[4])[jn]  : ((const float*)&q[5])[jn-4];
            float e3 = (jn<4)? ((const float*)&q[6])[jn]  : ((const float*)&q[7])[jn-4];
            float e4 = (jn<4)? ((const float*)&q[8])[jn]  : ((const float*)&q[9])[jn-4];
            float e5 = (jn<4)? ((const float*)&q[10])[jn] : ((const float*)&q[11])[jn-4];
            float e6 = (jn<4)? ((const float*)&q[12])[jn] : ((const float*)&q[13])[jn-4];
            float e7 = (jn<4)? ((const float*)&q[14])[jn] : ((const float*)&q[15])[jn-4];
            uint4 wv;
            wv.x = pack2_bf(e0, e1); wv.y = pack2_bf(e2, e3);
            wv.z = pack2_bf(e4, e5); wv.w = pack2_bf(e6, e7);
            *(uint4*)&Bs[n*40 + ((((bk8>>3) ^ (n&3))) << 3)] = wv;
        }
        __syncthreads();
        const ushort* ab = As + c15*40 + gx;
        #pragma unroll
        for (int nt = 0; nt < 8; nt++) {
            int n = w*128 + nt*16 + c15;
            bf16x8 af  = *(const bf16x8*)ab;
            bf16x8 bfr = *(const bf16x8*)&Bs[n*40 + gx];
            acc1[nt] = __builtin_amdgcn_mfma_f32_16x16x32_bf16(af, bfr, acc1[nt], 0, 0, 0);
        }
    }
    __syncthreads();

    if (g < 2) {
        #pragma unroll
        for (int nt = 0; nt < 8; nt++) {
            int c = w*128 + nt*16 + c15;
            float bias = b1[c];
            #pragma unroll
            for (int i = 0; i < 4; i++) {
                int r = g*4 + i;
                float v = acc1[nt][i] + bias;
                v = 0.5f * v * (1.0f + erff(v * 0.70710678118654752f));
                lnb[r*513 + c] = v;
            }
        }
    }
    __syncthreads();
    if (tid < 128) {
        int rr = tid >> 4, sl = tid & 15;
        float sum = 0.f, sq = 0.f;
        #pragma unroll
        for (int j = 0; j < 32; j++) {
            float v = lnb[rr*513 + sl + 16*j];
            sum += v; sq += v*v;
        }
        #pragma unroll
        for (int m = 1; m < 16; m <<= 1) { sum += __shfl_xor(sum, m); sq += __shfl_xor(sq, m); }
        if (sl == 0) {
            float mean = sum * (1.0f/(2*D_));
            float var  = fmaxf(sq * (1.0f/(2*D_)) - mean*mean, 0.f);
            stat[rr] = make_float2(mean, rsqrtf(var + 1e-12f));
        }
    }
    __syncthreads();
    if (tid < 128) {
        int rr = tid & 7, s2 = tid >> 3;
        float2 ms = stat[rr];
        int c0 = s2 * 32;
        #pragma unroll
        for (int q = 0; q < 8; q++) {
            int c = c0 + q*4;
            float4 v = *(const float4*)&lnb[rr*513 + c];
            float4 gm = *(const float4*)&gf[c];
            float4 bt = *(const float4*)&bfv[c];
            float h0 = (v.x - ms.x)*ms.y*gm.x + bt.x;
            float h1 = (v.y - ms.x)*ms.y*gm.y + bt.y;
            float h2 = (v.z - ms.x)*ms.y*gm.z + bt.z;
            float h3 = (v.w - ms.x)*ms.y*gm.w + bt.w;
            *(uint2*)&fout[(size_t)(m0+rr)*(2*D_) + c] = make_uint2(pack2_bf(h0,h1), pack2_bf(h2,h3));
        }
    }
}

// ---- gemm_f2: out = f@W2 + b2f + resid ----
__global__ __launch_bounds__(256, 4)
void gemm_f2(const ushort* __restrict__ fbuf, const float* __restrict__ W2,
             const float* __restrict__ b2f, const float* __restrict__ resid,
             float* __restrict__ outp)
{
    __shared__ __align__(16) ushort As[16*40];
    __shared__ __align__(16) ushort Bs[256*40];
    __shared__ float esc[8*257];

    int m0 = blockIdx.x * 8;
    int tid = threadIdx.x;
    int lane = tid & 63;
    int w = tid >> 6;
    int g = lane >> 4, c15 = lane & 15;
    int gx = (g ^ (c15 & 3)) * 8;

    int am  = tid >> 4;
    int ak2 = (tid & 15) * 2;
    int apos = am*40 + ((((ak2>>3) ^ (am&3))) << 3) + (ak2 & 7);
    int bn8 = (tid & 31) * 8;
    int bkq = (tid >> 5) * 4;
    int bposR = ((bkq >> 3) << 3) + (bkq & 7);

    f32x4 acc[4];
    #pragma unroll
    for (int j = 0; j < 4; j++) acc[j] = (f32x4){0.f,0.f,0.f,0.f};

    for (int ksi = 0; ksi < 16; ksi++) {
        int k0 = ksi * 32;
        uint av = 0;
        if (tid < 128) av = *(const uint*)&fbuf[(size_t)(m0+am)*(2*D_) + k0 + ak2];
        float4 lo[4], hi[4];
        #pragma unroll
        for (int i = 0; i < 4; i++) {
            lo[i] = *(const float4*)&W2[(size_t)(k0+bkq+i)*D_ + bn8];
            hi[i] = *(const float4*)&W2[(size_t)(k0+bkq+i)*D_ + bn8 + 4];
        }
        if (ksi) __syncthreads();
        if (tid < 128) *(uint*)&As[apos] = av;
        #pragma unroll
        for (int jn = 0; jn < 8; jn++) {
            int n = bn8 + jn;
            float v0 = (jn<4)? ((const float*)&lo[0])[jn] : ((const float*)&hi[0])[jn-4];
            float v1 = (jn<4)? ((const float*)&lo[1])[jn] : ((const float*)&hi[1])[jn-4];
            float v2 = (jn<4)? ((const float*)&lo[2])[jn] : ((const float*)&hi[2])[jn-4];
            float v3 = (jn<4)? ((const float*)&lo[3])[jn] : ((const float*)&hi[3])[jn-4];
            uint2 wv; wv.x = pack2_bf(v0, v1); wv.y = pack2_bf(v2, v3);
            *(uint2*)&Bs[n*40 + (bposR ^ ((n&3)<<3))] = wv;
        }
        __syncthreads();
        const ushort* ab = As + c15*40 + gx;
        #pragma unroll
        for (int nt = 0; nt < 4; nt++) {
            int n = w*64 + nt*16 + c15;
            bf16x8 af  = *(const bf16x8*)ab;
            bf16x8 bfr = *(const bf16x8*)&Bs[n*40 + gx];
            acc[nt] = __builtin_amdgcn_mfma_f32_16x16x32_bf16(af, bfr, acc[nt], 0, 0, 0);
        }
    }
    __syncthreads();

    if (g < 2) {
        #pragma unroll
        for (int nt = 0; nt < 4; nt++) {
            int c = w*64 + nt*16 + c15;
            #pragma unroll
            for (int i = 0; i < 4; i++)
                esc[(g*4+i)*257 + c] = acc[nt][i];
        }
    }
    __syncthreads();
    if (tid < 128) {
        int rr = tid & 7, s2 = tid >> 3;
        int c0 = s2 * 16;
        #pragma unroll
        for (int q = 0; q < 4; q++) {
            int c = c0 + q*4;
            float4 v  = *(const float4*)&esc[rr*257 + c];
            float4 bb = *(const float4*)&b2f[c];
            float4 rs = *(const float4*)&resid[(size_t)(m0+rr)*D_ + c];
            float4 o = make_float4(v.x+bb.x+rs.x, v.y+bb.y+rs.y, v.z+bb.z+rs.z, v.w+bb.w+rs.w);
            *(float4*)&outp[(size_t)(m0+rr)*D_ + c] = o;
        }
    }
}

extern "C" void kernel_launch(void* const* d_in, const int* in_sizes, int n_in,
                              void* d_out, int out_size, void* d_ws, size_t ws_size,
                              hipStream_t stream)
{
    const float* adj    = (const float*)d_in[0];
    const float* degree = (const float*)d_in[1];
    const float* x      = (const float*)d_in[2];
    const float* kern   = (const float*)d_in[3];
    const float* Wv     = (const float*)d_in[4];
    const float* Bv     = (const float*)d_in[5];
    const float* W0     = (const float*)d_in[6];
    const float* gamma2 = (const float*)d_in[7];
    const float* beta2  = (const float*)d_in[8];
    const float* W1     = (const float*)d_in[9];
    const float* b1     = (const float*)d_in[10];
    const float* gf     = (const float*)d_in[11];
    const float* bf_    = (const float*)d_in[12];
    const float* W2     = (const float*)d_in[13];
    const float* b2f    = (const float*)d_in[14];
    float* out = (float*)d_out;
    float* ws  = (float*)d_ws;

    size_t off = 0;
    float* T0    = ws + off; off += (size_t)ROWS_*D_/2;     // bf16 panels (1MB)
    float* T1    = ws + off; off += (size_t)ROWS_*D_/2;
    float* resid = ws + off; off += (size_t)ROWS_*D_;       // fp32
    float* hbufF = ws + off; off += (size_t)ROWS_*D_/2;     // bf16
    float* foutF = ws + off; off += (size_t)ROWS_*D_;       // bf16 (2D cols)
    float* PpF   = ws + off; off += (size_t)KS_*ROWS_*D_/2; // bf16 slabs (8MB)
    ushort* adjp = (ushort*)(ws + off);                      // 37.75MB bf16

    ushort* T0b = (ushort*)T0;
    ushort* T1b = (ushort*)T1;
    ushort* hb  = (ushort*)hbufF;
    ushort* fb  = (ushort*)foutF;
    ushort* Pp  = (ushort*)PpF;

    gemm_v<<<dim3(ROWS_/64, D_/64), 256, 0, stream>>>(x, Wv, Bv, T0b);

    int chain_grid  = B_*64*KS_;     // 1024
    int reduce_grid = SLABU2_/256;   // 512
    chain_mfma<1><<<chain_grid, 256, 0, stream>>>(adj, adjp, kern, T0b, Pp, 3);
    chain_reduce<<<reduce_grid, 256, 0, stream>>>(Pp, T1b);
    chain_mfma<0><<<chain_grid, 256, 0, stream>>>(adj, adjp, kern, T1b, Pp, 2);
    chain_reduce<<<reduce_grid, 256, 0, stream>>>(Pp, T0b);
    chain_mfma<0><<<chain_grid, 256, 0, stream>>>(adj, adjp, kern, T0b, Pp, 1);
    chain_reduce<<<reduce_grid, 256, 0, stream>>>(Pp, T1b);
    chain_mfma<0><<<chain_grid, 256, 0, stream>>>(adj, adjp, kern, T1b, Pp, 0);

    gemm_r <<<ROWS_/8, 256, 0, stream>>>(Pp, degree, W0, x, gamma2, beta2, resid, hb);
    gemm_f1<<<ROWS_/8, 256, 0, stream>>>(hb, W1, b1, gf, bf_, fb);
    gemm_f2<<<ROWS_/8, 256, 0, stream>>>(fb, W2, b2f, resid, out);
}